// Round 23
// baseline (337.734 us; speedup 1.0000x reference)
//
#include <hip/hip_runtime.h>
#include <math.h>

#define NB 2
#define HB 8
#define LB 2048
#define EB 64
#define BITSN 32
#define CLN 128
#define ITERS 10
#define TOPKN 32
#define NEGV -10000000.0f

typedef unsigned long long u64;
typedef unsigned int u32;

// u16-packed partials: part[nh][j*64 + c/2], fields (c even | c odd << 16),
// j = 0..31 bit-sums, j = 32 counts. All values <= 2048 -> no carry between
// fields under u32 atomicAdd (max field sum 4096 < 65536): exact.
#define PART_NH16 (33 * 64)                     // 2112 dwords per nh
#define PART_ITER16 (NB * HB * PART_NH16)       // 33792 dwords per iteration
#define PART_TOTAL16 (ITERS * PART_ITER16)      // 337920 dwords (~1.35 MB)
#define BITS_BLOCKS 4096                        // NQ/8
#define ZBLOCKS ((PART_TOTAL16 + 255) / 256)

// ---------------------------------------------------------------------------
// Kernel 1: LSH bits (blocks < BITS_BLOCKS) + zeroing of packed partials.
// ---------------------------------------------------------------------------
__global__ __launch_bounds__(256) void bits_zero_kernel(const float* __restrict__ q,
                                                        const float* __restrict__ planes,
                                                        u32* __restrict__ bits,
                                                        u32* __restrict__ zbuf) {
    int tid = threadIdx.x;
    int bid = blockIdx.x;
    if (bid >= BITS_BLOCKS) {
        int i = (bid - BITS_BLOCKS) * 256 + tid;
        if (i < PART_TOTAL16) zbuf[i] = 0u;
        return;
    }
    int wave = tid >> 6;
    int lane = tid & 63;
    int b = lane & 31;
    int which = lane >> 5;
    int qi = bid * 8 + wave * 2 + which;   // qi = (n*H + h)*L + l
    int l = qi & (LB - 1);
    int nh = qi / LB;
    int h = nh & (HB - 1);
    int n = nh / HB;
    const float* qrow = q + (((long long)n * LB + l) * HB + h) * EB;
    const float* prow = planes + b * (EB + 1);
    double acc = (double)prow[EB];                 // bias (the ones column)
    #pragma unroll 8
    for (int e = 0; e < EB; ++e) acc += (double)qrow[e] * (double)prow[e];
    unsigned long long m = __ballot(acc > 0.0);
    if (b == 0) {
        bits[qi] = (u32)(which ? (m >> 32) : (m & 0xffffffffULL));
    }
}

// ---------------------------------------------------------------------------
// K-means iteration: 128 blocks (16 nh x 8 tiles of 256 points), 256 thr.
// u16-packed partials; packed-key argmin (== first-min); per-set-bit LDS
// histogram of OWN 256 points; packed atomic dump (exact, deterministic).
// ---------------------------------------------------------------------------
__global__ __launch_bounds__(256) void kmeans_iter_kernel(const u32* __restrict__ bits,
                                                          const u32* __restrict__ part_prev,
                                                          u32* __restrict__ part_cur,
                                                          const u32* __restrict__ cent_prev_g,
                                                          u32* __restrict__ cent_cur_g,
                                                          int it) {
    __shared__ u32 cent[CLN];
    __shared__ int hist[33 * 128];       // unpacked [j*128+c]
    int tid = threadIdx.x;
    int bid = blockIdx.x;
    int nh = bid >> 3;
    int tile = bid & 7;
    int lane = tid & 63;

    for (int i = tid; i < 33 * 128; i += 256) hist[i] = 0;
    if (tid < CLN) {
        u32 cv;
        if (it == 0) {
            cv = bits[nh * LB + tid * (LB / CLN)];        // init_idx = 16c
        } else {
            const u32* pp = part_prev + nh * PART_NH16;
            int sh = (tid & 1) * 16;
            int cnt = (int)((pp[32 * 64 + (tid >> 1)] >> sh) & 0xffffu);
            u32 nb = 0u;
            #pragma unroll
            for (int j = 0; j < BITSN; ++j) {
                int s = (int)((pp[j * 64 + (tid >> 1)] >> sh) & 0xffffu);
                if (2 * s >= cnt) nb |= (1u << j);
            }
            cv = (cnt > 0) ? nb : cent_prev_g[nh * CLN + tid];
        }
        cent[tid] = cv;
        if (tile == 0) cent_cur_g[nh * CLN + tid] = cv;   // materialize chain
    }
    __syncthreads();

    int l = tile * 256 + tid;
    u32 bv = bits[nh * LB + l];

    // ---- argmin via packed key (d<<7)|c : min == first-min tie rule
    u32 clo = cent[lane], chi = cent[lane + 64];
    u32 best = 0x7fffffffu;
    #pragma unroll 16
    for (int c = 0; c < 64; ++c) {
        u32 cc = (u32)__builtin_amdgcn_readlane((int)clo, c);
        u32 key = ((u32)__popc(bv ^ cc) << 7) | (u32)c;
        best = (key < best) ? key : best;
    }
    #pragma unroll 16
    for (int c = 0; c < 64; ++c) {
        u32 cc = (u32)__builtin_amdgcn_readlane((int)chi, c);
        u32 key = ((u32)__popc(bv ^ cc) << 7) | (u32)(64 + c);
        best = (key < best) ? key : best;
    }
    int bc = (int)(best & 127u);

    // ---- per-set-bit LDS histogram (exact integer adds)
    atomicAdd(&hist[32 * 128 + bc], 1);
    u32 bb = bv;
    while (bb) { int j = __ffs(bb) - 1; atomicAdd(&hist[j * 128 + bc], 1); bb &= bb - 1; }
    __syncthreads();

    // ---- u16-packed dump (pair c=2p, 2p+1); skip zero pairs
    u32* pc = part_cur + nh * PART_NH16;
    for (int i = tid; i < PART_NH16; i += 256) {
        int j = i >> 6, p = i & 63;
        u32 v = (u32)hist[j * 128 + 2 * p] | ((u32)hist[j * 128 + 2 * p + 1] << 16);
        if (v) atomicAdd(&pc[i], v);
    }
}

// ---------------------------------------------------------------------------
// Kernel 3: final assignment + lists fused, 16 blocks x 1024 thr.
// ---------------------------------------------------------------------------
__global__ __launch_bounds__(1024) void list_final_kernel(const u32* __restrict__ bits,
                                                          const u32* __restrict__ part_prev,
                                                          const u32* __restrict__ cent_prev_g,
                                                          int* __restrict__ csort_g,
                                                          int* __restrict__ cnt_g,
                                                          int* __restrict__ ofs_g,
                                                          int* __restrict__ list_g) {
    __shared__ u32 cent[CLN];
    __shared__ int cnt[CLN];
    __shared__ int cntw[2][16][CLN];       // (group, wave, cluster)
    __shared__ int ofs[CLN];
    int nh = blockIdx.x;
    int tid = threadIdx.x;
    int w = tid >> 6, lane = tid & 63;

    if (tid < CLN) {
        const u32* pp = part_prev + nh * PART_NH16;
        int sh = (tid & 1) * 16;
        int cn = (int)((pp[32 * 64 + (tid >> 1)] >> sh) & 0xffffu);
        u32 nb = 0u;
        #pragma unroll
        for (int j = 0; j < BITSN; ++j) {
            int s = (int)((pp[j * 64 + (tid >> 1)] >> sh) & 0xffffu);
            if (2 * s >= cn) nb |= (1u << j);
        }
        cent[tid] = (cn > 0) ? nb : cent_prev_g[nh * CLN + tid];
        cnt[tid] = 0;
    }
    for (int i = tid; i < 2 * 16 * CLN; i += 1024) (&cntw[0][0][0])[i] = 0;
    __syncthreads();

    int l0 = tid, l1 = tid + 1024;
    u32 bv0 = bits[nh * LB + l0];
    u32 bv1 = bits[nh * LB + l1];
    u32 clo = cent[lane], chi = cent[lane + 64];
    u32 best0 = 0x7fffffffu, best1 = 0x7fffffffu;
    #pragma unroll 16
    for (int c = 0; c < 64; ++c) {
        u32 cc = (u32)__builtin_amdgcn_readlane((int)clo, c);
        u32 k0 = ((u32)__popc(bv0 ^ cc) << 7) | (u32)c;
        u32 k1 = ((u32)__popc(bv1 ^ cc) << 7) | (u32)c;
        best0 = (k0 < best0) ? k0 : best0;
        best1 = (k1 < best1) ? k1 : best1;
    }
    #pragma unroll 16
    for (int c = 0; c < 64; ++c) {
        u32 cc = (u32)__builtin_amdgcn_readlane((int)chi, c);
        u32 k0 = ((u32)__popc(bv0 ^ cc) << 7) | (u32)(64 + c);
        u32 k1 = ((u32)__popc(bv1 ^ cc) << 7) | (u32)(64 + c);
        best0 = (k0 < best0) ? k0 : best0;
        best1 = (k1 < best1) ? k1 : best1;
    }
    int bc0 = (int)(best0 & 127u);
    int bc1 = (int)(best1 & 127u);
    u64 ltmask = (lane == 0) ? 0ULL : (~0ULL >> (64 - lane));

    int rank0 = 0, rank1 = 0;
    for (int c = 0; c < CLN; ++c) {
        u64 m0 = __ballot(bc0 == c);
        u64 m1 = __ballot(bc1 == c);
        if ((m0 | m1) == 0ULL) continue;
        if (bc0 == c) rank0 = (int)__popcll(m0 & ltmask);
        if (bc1 == c) rank1 = (int)__popcll(m1 & ltmask);
        if (lane == 0) {
            int p0 = (int)__popcll(m0), p1 = (int)__popcll(m1);
            if (p0) cntw[0][w][c] = p0;
            if (p1) cntw[1][w][c] = p1;
            atomicAdd(&cnt[c], p0 + p1);
        }
    }
    __syncthreads();
    if (tid == 0) {
        int run = 0;
        for (int c = 0; c < CLN; ++c) { ofs[c] = run; run += cnt[c]; }
    }
    __syncthreads();
    if (tid < CLN) {           // absolute bases per (g,w) in ascending-l order
        int c = tid;
        int run = ofs[c];
        #pragma unroll
        for (int g = 0; g < 2; ++g)
            for (int ww = 0; ww < 16; ++ww) {
                int t = cntw[g][ww][c];
                cntw[g][ww][c] = run;
                run += t;
            }
        cnt_g[nh * CLN + c] = cnt[c];
        ofs_g[nh * CLN + c] = ofs[c];
    }
    __syncthreads();
    {
        int p0 = cntw[0][w][bc0] + rank0;
        int p1 = cntw[1][w][bc1] + rank1;
        list_g[nh * LB + p0] = l0;
        list_g[nh * LB + p1] = l1;
        csort_g[nh * LB + p0] = bc0;        // cluster id at list position
        csort_g[nh * LB + p1] = bc1;
    }
}

// ---------------------------------------------------------------------------
// Kernel 3b: Qg chip-wide. Block per (nh,c) x 4 waves; f64, fixed order.
// ---------------------------------------------------------------------------
__global__ __launch_bounds__(256) void qg_kernel(const float* __restrict__ q,
                                                 const int* __restrict__ cnt_g,
                                                 const int* __restrict__ ofs_g,
                                                 const int* __restrict__ list_g,
                                                 float* __restrict__ qgf) {
    __shared__ double ps[4][EB];
    int bid = blockIdx.x;            // nh*128 + c
    int nh = bid >> 7;
    int h = nh & (HB - 1);
    int n = nh / HB;
    int tid = threadIdx.x;
    int w = tid >> 6, lane = tid & 63;
    int cn = cnt_g[bid];
    int o = ofs_g[bid];
    const int* lp = list_g + nh * LB + o;
    double acc = 0.0;
    for (int i = w; i < cn; i += 4) {
        int l = lp[i];
        acc += (double)q[(((long long)n * LB + l) * HB + h) * EB + lane];
    }
    ps[w][lane] = acc;
    __syncthreads();
    if (tid < EB) {
        double s = ((ps[0][tid] + ps[1][tid]) + ps[2][tid]) + ps[3][tid];
        double dcn = (double)(cn > 0 ? cn : 1);
        qgf[(long long)bid * EB + tid] = (float)(s / dcn);
    }
}

// ---------------------------------------------------------------------------
// Kernel 4: scores with LDS-staged Qg (R20-verified). 512 blocks (nh x 32
// tiles of 64 rows) x 4 waves; block stages the nh's 32 KB Qg in LDS once;
// each wave holds 64 K rows in registers, 32-cluster slice, 4-way split
// accumulators (fixed combine). Coalesced key stores.
// ---------------------------------------------------------------------------
__global__ __launch_bounds__(256) void scores_kernel(const float* __restrict__ kk,
                                                     const float* __restrict__ qgf,
                                                     u32* __restrict__ keys) {
    __shared__ float qs[CLN * EB];   // 32 KB
    int bid = blockIdx.x;            // nh*32 + tile (64-row tiles)
    int nh = bid >> 5;
    int tile = bid & 31;
    int h = nh & (HB - 1);
    int n = nh / HB;
    int tid = threadIdx.x;
    int w = tid >> 6;
    int lane = tid & 63;
    int l = tile * 64 + lane;        // my row
    int cbase = w * 32;              // 32-cluster slice per wave

    // cooperative stage: 2048 float4 = 32 KB, coalesced
    {
        const float4* src = (const float4*)(qgf + (long long)nh * CLN * EB);
        float4* dst = (float4*)qs;
        #pragma unroll
        for (int i = 0; i < 8; ++i) dst[tid + 256 * i] = src[tid + 256 * i];
    }

    const float4* kr4 = (const float4*)(kk + (((long long)n * LB + l) * HB + h) * EB);
    float rr[EB];
    #pragma unroll
    for (int i = 0; i < 16; ++i) {
        float4 t4 = kr4[i];
        rr[4 * i] = t4.x; rr[4 * i + 1] = t4.y; rr[4 * i + 2] = t4.z; rr[4 * i + 3] = t4.w;
    }
    __syncthreads();

    for (int c = 0; c < 32; ++c) {
        const float4* qp = (const float4*)(qs + (cbase + c) * EB);  // LDS broadcast
        float a0 = 0.f, a1 = 0.f, a2 = 0.f, a3 = 0.f;
        #pragma unroll
        for (int i = 0; i < 4; ++i) {
            float4 q0 = qp[i], q1 = qp[4 + i], q2 = qp[8 + i], q3 = qp[12 + i];
            int e0 = 4 * i, e1 = 16 + 4 * i, e2 = 32 + 4 * i, e3 = 48 + 4 * i;
            a0 = fmaf(q0.x, rr[e0], a0); a0 = fmaf(q0.y, rr[e0 + 1], a0);
            a0 = fmaf(q0.z, rr[e0 + 2], a0); a0 = fmaf(q0.w, rr[e0 + 3], a0);
            a1 = fmaf(q1.x, rr[e1], a1); a1 = fmaf(q1.y, rr[e1 + 1], a1);
            a1 = fmaf(q1.z, rr[e1 + 2], a1); a1 = fmaf(q1.w, rr[e1 + 3], a1);
            a2 = fmaf(q2.x, rr[e2], a2); a2 = fmaf(q2.y, rr[e2 + 1], a2);
            a2 = fmaf(q2.z, rr[e2 + 2], a2); a2 = fmaf(q2.w, rr[e2 + 3], a2);
            a3 = fmaf(q3.x, rr[e3], a3); a3 = fmaf(q3.y, rr[e3 + 1], a3);
            a3 = fmaf(q3.z, rr[e3 + 2], a3); a3 = fmaf(q3.w, rr[e3 + 3], a3);
        }
        float acc = (a0 + a1) + (a2 + a3);   // fixed deterministic combine
        u32 u = __float_as_uint(acc);
        u = ((int)u < 0) ? ~u : (u | 0x80000000u);          // monotone f32->u32
        keys[((long long)(nh * CLN + cbase + c)) * LB + l] = u;
    }
}

// ---------------------------------------------------------------------------
// Kernel 5: top-32 per (n,h,c) via block-wide BITONIC SORT in LDS.
// 2048 blocks x 256 thr. Keys packed (key<<32)|(2047-l): u64 comparator over
// distinct values -> unique total order == (value desc, index asc), i.e.
// exactly the tournament's output, bit-identical tki.
// ---------------------------------------------------------------------------
__global__ __launch_bounds__(256) void topsel_kernel(const u32* __restrict__ keys,
                                                     int* __restrict__ tki_g) {
    __shared__ u64 sk[LB];           // 16 KB
    int bid = blockIdx.x;            // nh*128 + c
    int tid = threadIdx.x;
    const u32* kp = keys + (long long)bid * LB;
    #pragma unroll
    for (int t = 0; t < 8; ++t) {
        int i = tid + 256 * t;
        sk[i] = ((u64)kp[i] << 32) | (u32)(2047 - i);
    }
    __syncthreads();

    // descending bitonic sort of 2048 u64s
    for (int k = 2; k <= LB; k <<= 1) {
        for (int j = k >> 1; j > 0; j >>= 1) {
            #pragma unroll
            for (int t = 0; t < 8; ++t) {
                int i = tid + 256 * t;
                int ixj = i ^ j;
                if (ixj > i) {
                    u64 a = sk[i], b = sk[ixj];
                    bool up = ((i & k) == 0);          // up-region: descending
                    if (up ? (a < b) : (a > b)) { sk[i] = b; sk[ixj] = a; }
                }
            }
            __syncthreads();
        }
    }
    if (tid < TOPKN) tki_g[bid * TOPKN + tid] = 2047 - (int)(sk[tid] & 2047u);
}

// ---------------------------------------------------------------------------
// Per-query attention body (R15-verified math, byte-identical semantics).
// ---------------------------------------------------------------------------
__device__ __forceinline__ void attn_one(const float* __restrict__ q,
                                         const float* __restrict__ kk,
                                         const float* __restrict__ vv,
                                         int n, int h, int l,
                                         const int* __restrict__ krow,
                                         int lane, float* __restrict__ out) {
    int j = lane & 31, p = lane >> 5;
    int kidx = krow[j];
    const float* vbase = vv + ((long long)n * LB * HB + h) * EB;
    float vreg[TOPKN];
    #pragma unroll
    for (int jj = 0; jj < TOPKN; ++jj) {
        int kj = __shfl(kidx, jj);
        vreg[jj] = vbase[(long long)kj * (HB * EB) + lane];
    }
    const float4* q4 = (const float4*)(q + (((long long)n * LB + l) * HB + h) * EB) + p * 8;
    const float4* k4 = (const float4*)(kk + (((long long)n * LB + kidx) * HB + h) * EB) + p * 8;
    float part = 0.f;
    #pragma unroll
    for (int i = 0; i < 8; ++i) {
        float4 a = q4[i], b = k4[i];
        part += a.x * b.x + a.y * b.y + a.z * b.z + a.w * b.w;
    }
    float qlo = __shfl(part, j);
    float qhi = __shfl(part, j + 32);
    float qk = qlo + qhi;
    bool future = kidx > l;
    float logit = 0.125f * (future ? NEGV : qk);
    float m = logit;
    #pragma unroll
    for (int off = 16; off; off >>= 1) m = fmaxf(m, __shfl_xor(m, off));
    float ex = expf(logit - m);
    float ssum = ex;
    #pragma unroll
    for (int off = 16; off; off >>= 1) ssum += __shfl_xor(ssum, off);
    float a = future ? 0.f : ex / ssum;
    float oacc = 0.f;
    #pragma unroll
    for (int jj = 0; jj < TOPKN; ++jj) {
        float aj = __shfl(a, jj);
        oacc = fmaf(aj, vreg[jj], oacc);
    }
    out[(((long long)n * LB + l) * HB + h) * EB + lane] = oacc;
}

// ---------------------------------------------------------------------------
// Shared-pair attention body (R17-verified shared path, byte-identical).
// ---------------------------------------------------------------------------
__device__ __forceinline__ void attn_pair_body(const float* __restrict__ q,
                                               const float* __restrict__ kk,
                                               const float* __restrict__ vv,
                                               int n, int h, int l0, int l1,
                                               const int* __restrict__ krow,
                                               int lane, float* __restrict__ out) {
    int j = lane & 31, p = lane >> 5;
    int kidx = krow[j];
    const float* vbase = vv + ((long long)n * LB * HB + h) * EB;
    float vreg[TOPKN];
    #pragma unroll
    for (int jj = 0; jj < TOPKN; ++jj) {
        int kj = __shfl(kidx, jj);
        vreg[jj] = vbase[(long long)kj * (HB * EB) + lane];
    }
    const float4* q40 = (const float4*)(q + (((long long)n * LB + l0) * HB + h) * EB) + p * 8;
    const float4* q41 = (const float4*)(q + (((long long)n * LB + l1) * HB + h) * EB) + p * 8;
    const float4* k4  = (const float4*)(kk + (((long long)n * LB + kidx) * HB + h) * EB) + p * 8;
    float part0 = 0.f, part1 = 0.f;
    #pragma unroll
    for (int i = 0; i < 8; ++i) {
        float4 b = k4[i];
        float4 a0 = q40[i], a1 = q41[i];
        part0 += a0.x * b.x + a0.y * b.y + a0.z * b.z + a0.w * b.w;
        part1 += a1.x * b.x + a1.y * b.y + a1.z * b.z + a1.w * b.w;
    }
    float qk0 = __shfl(part0, j) + __shfl(part0, j + 32);
    float qk1 = __shfl(part1, j) + __shfl(part1, j + 32);
    bool fut0 = kidx > l0, fut1 = kidx > l1;
    float lg0 = 0.125f * (fut0 ? NEGV : qk0);
    float lg1 = 0.125f * (fut1 ? NEGV : qk1);
    float m0 = lg0, m1 = lg1;
    #pragma unroll
    for (int off = 16; off; off >>= 1) {
        m0 = fmaxf(m0, __shfl_xor(m0, off));
        m1 = fmaxf(m1, __shfl_xor(m1, off));
    }
    float e0 = expf(lg0 - m0), e1 = expf(lg1 - m1);
    float s0 = e0, s1 = e1;
    #pragma unroll
    for (int off = 16; off; off >>= 1) {
        s0 += __shfl_xor(s0, off);
        s1 += __shfl_xor(s1, off);
    }
    float a0 = fut0 ? 0.f : e0 / s0;
    float a1 = fut1 ? 0.f : e1 / s1;
    float o0 = 0.f, o1 = 0.f;
    #pragma unroll
    for (int jj = 0; jj < TOPKN; ++jj) {
        float aj0 = __shfl(a0, jj);
        float aj1 = __shfl(a1, jj);
        o0 = fmaf(aj0, vreg[jj], o0);
        o1 = fmaf(aj1, vreg[jj], o1);
    }
    out[(((long long)n * LB + l0) * HB + h) * EB + lane] = o0;
    out[(((long long)n * LB + l1) * HB + h) * EB + lane] = o1;
}

// ---------------------------------------------------------------------------
// Kernel 6: QUAD gather attention in CLUSTER-SORTED order. All-same quads
// take the 4-way shared path; mixed quads decompose into per-half pair
// checks (pair shared path or attn_one x2). All branches wave-uniform;
// per-query math byte-identical to the verified kernels.
// ---------------------------------------------------------------------------
__global__ __launch_bounds__(256) void attn_quad_kernel(const float* __restrict__ q,
                                                        const float* __restrict__ kk,
                                                        const float* __restrict__ vv,
                                                        const int* __restrict__ list_g,
                                                        const int* __restrict__ csort_g,
                                                        const int* __restrict__ tki_g,
                                                        float* __restrict__ out) {
    int tid = threadIdx.x;
    int wave = tid >> 6, lane = tid & 63;
    int idx = blockIdx.x * 4 + wave;  // quad index: nh*(L/4) + qd
    int nh = idx >> 9;                // LB/4 = 512 quads per nh
    int qd = idx & 511;
    int pos = 4 * qd;
    int l0 = list_g[nh * LB + pos];
    int l1 = list_g[nh * LB + pos + 1];
    int l2 = list_g[nh * LB + pos + 2];
    int l3 = list_g[nh * LB + pos + 3];
    int c0 = csort_g[nh * LB + pos];
    int c1 = csort_g[nh * LB + pos + 1];
    int c2 = csort_g[nh * LB + pos + 2];
    int c3 = csort_g[nh * LB + pos + 3];
    int h = nh & (HB - 1);
    int n = nh / HB;

    if ((c0 != c1) | (c1 != c2) | (c2 != c3)) {   // wave-uniform decompose
        if (c0 == c1) {
            attn_pair_body(q, kk, vv, n, h, l0, l1, tki_g + (nh * CLN + c0) * TOPKN, lane, out);
        } else {
            attn_one(q, kk, vv, n, h, l0, tki_g + (nh * CLN + c0) * TOPKN, lane, out);
            attn_one(q, kk, vv, n, h, l1, tki_g + (nh * CLN + c1) * TOPKN, lane, out);
        }
        if (c2 == c3) {
            attn_pair_body(q, kk, vv, n, h, l2, l3, tki_g + (nh * CLN + c2) * TOPKN, lane, out);
        } else {
            attn_one(q, kk, vv, n, h, l2, tki_g + (nh * CLN + c2) * TOPKN, lane, out);
            attn_one(q, kk, vv, n, h, l3, tki_g + (nh * CLN + c3) * TOPKN, lane, out);
        }
        return;
    }

    // ---- shared path: one tki row, one V-preload, one K row set
    const int* krow = tki_g + (nh * CLN + c0) * TOPKN;
    int j = lane & 31, p = lane >> 5;
    int kidx = krow[j];
    const float* vbase = vv + ((long long)n * LB * HB + h) * EB;
    float vreg[TOPKN];
    #pragma unroll
    for (int jj = 0; jj < TOPKN; ++jj) {
        int kj = __shfl(kidx, jj);
        vreg[jj] = vbase[(long long)kj * (HB * EB) + lane];
    }

    const float4* q40 = (const float4*)(q + (((long long)n * LB + l0) * HB + h) * EB) + p * 8;
    const float4* q41 = (const float4*)(q + (((long long)n * LB + l1) * HB + h) * EB) + p * 8;
    const float4* q42 = (const float4*)(q + (((long long)n * LB + l2) * HB + h) * EB) + p * 8;
    const float4* q43 = (const float4*)(q + (((long long)n * LB + l3) * HB + h) * EB) + p * 8;
    const float4* k4  = (const float4*)(kk + (((long long)n * LB + kidx) * HB + h) * EB) + p * 8;
    float p0 = 0.f, p1 = 0.f, p2 = 0.f, p3 = 0.f;
    #pragma unroll
    for (int i = 0; i < 8; ++i) {
        float4 b = k4[i];
        float4 a0 = q40[i], a1 = q41[i], a2 = q42[i], a3 = q43[i];
        p0 += a0.x * b.x + a0.y * b.y + a0.z * b.z + a0.w * b.w;
        p1 += a1.x * b.x + a1.y * b.y + a1.z * b.z + a1.w * b.w;
        p2 += a2.x * b.x + a2.y * b.y + a2.z * b.z + a2.w * b.w;
        p3 += a3.x * b.x + a3.y * b.y + a3.z * b.z + a3.w * b.w;
    }
    float qk0 = __shfl(p0, j) + __shfl(p0, j + 32);
    float qk1 = __shfl(p1, j) + __shfl(p1, j + 32);
    float qk2 = __shfl(p2, j) + __shfl(p2, j + 32);
    float qk3 = __shfl(p3, j) + __shfl(p3, j + 32);

    bool f0 = kidx > l0, f1 = kidx > l1, f2 = kidx > l2, f3 = kidx > l3;
    float g0 = 0.125f * (f0 ? NEGV : qk0);
    float g1 = 0.125f * (f1 ? NEGV : qk1);
    float g2 = 0.125f * (f2 ? NEGV : qk2);
    float g3 = 0.125f * (f3 ? NEGV : qk3);
    float m0 = g0, m1 = g1, m2 = g2, m3 = g3;
    #pragma unroll
    for (int off = 16; off; off >>= 1) {
        m0 = fmaxf(m0, __shfl_xor(m0, off));
        m1 = fmaxf(m1, __shfl_xor(m1, off));
        m2 = fmaxf(m2, __shfl_xor(m2, off));
        m3 = fmaxf(m3, __shfl_xor(m3, off));
    }
    float e0 = expf(g0 - m0), e1 = expf(g1 - m1);
    float e2 = expf(g2 - m2), e3 = expf(g3 - m3);
    float s0 = e0, s1 = e1, s2 = e2, s3 = e3;
    #pragma unroll
    for (int off = 16; off; off >>= 1) {
        s0 += __shfl_xor(s0, off);
        s1 += __shfl_xor(s1, off);
        s2 += __shfl_xor(s2, off);
        s3 += __shfl_xor(s3, off);
    }
    float a0 = f0 ? 0.f : e0 / s0;
    float a1 = f1 ? 0.f : e1 / s1;
    float a2 = f2 ? 0.f : e2 / s2;
    float a3 = f3 ? 0.f : e3 / s3;

    float o0 = 0.f, o1 = 0.f, o2 = 0.f, o3 = 0.f;
    #pragma unroll
    for (int jj = 0; jj < TOPKN; ++jj) {
        float v = vreg[jj];
        o0 = fmaf(__shfl(a0, jj), v, o0);
        o1 = fmaf(__shfl(a1, jj), v, o1);
        o2 = fmaf(__shfl(a2, jj), v, o2);
        o3 = fmaf(__shfl(a3, jj), v, o3);
    }
    out[(((long long)n * LB + l0) * HB + h) * EB + lane] = o0;
    out[(((long long)n * LB + l1) * HB + h) * EB + lane] = o1;
    out[(((long long)n * LB + l2) * HB + h) * EB + lane] = o2;
    out[(((long long)n * LB + l3) * HB + h) * EB + lane] = o3;
}

// ---------------------------------------------------------------------------
extern "C" void kernel_launch(void* const* d_in, const int* in_sizes, int n_in,
                              void* d_out, int out_size, void* d_ws, size_t ws_size,
                              hipStream_t stream) {
    const float* q = (const float*)d_in[0];
    const float* k = (const float*)d_in[1];
    const float* v = (const float*)d_in[2];
    const float* planes = (const float*)d_in[3];
    float* out = (float*)d_out;

    const int NQ = NB * HB * LB;                  // 32768
    char* ws = (char*)d_ws;
    u32* bits     = (u32*)(ws);                    // 128 KB
    int* csort_g  = (int*)(ws + 0x20000);          // 128 KB (cluster per position)
    int* cnt_g    = (int*)(ws + 0x40000);          // 8 KB
    int* ofs_g    = (int*)(ws + 0x42000);          // 8 KB
    int* list_g   = (int*)(ws + 0x44000);          // 128 KB
    float* qgf    = (float*)(ws + 0x64000);        // 512 KB
    int* tki_g    = (int*)(ws + 0xE4000);          // 256 KB (2048 x 32 ints)
    u32* keys     = (u32*)(ws + 0x124000);         // 16 MB
    // clustering scratch ALIASES the keys region (dead once scores runs):
    u32* part_all = (u32*)(ws + 0x124000);         // 1.35 MB packed partials
    u32* cents0   = (u32*)(ws + 0x124000 + 0x180000);
    u32* cents1   = (u32*)(ws + 0x124000 + 0x182000);

    bits_zero_kernel<<<BITS_BLOCKS + ZBLOCKS, 256, 0, stream>>>(q, planes, bits, part_all);

    for (int it = 0; it < ITERS; ++it) {
        const u32* pp = part_all + (it == 0 ? 0 : (it - 1)) * PART_ITER16;
        u32* pc       = part_all + it * PART_ITER16;
        const u32* cprev = (it & 1) ? cents0 : cents1;   // cent_{it-1}
        u32* ccur        = (it & 1) ? cents1 : cents0;   // cent_it
        kmeans_iter_kernel<<<NB * HB * 8, 256, 0, stream>>>(bits, pp, pc, cprev, ccur, it);
    }
    // cent_10 from part[9] (carry cent_9, parity 1) + csort + lists
    list_final_kernel<<<NB * HB, 1024, 0, stream>>>(
        bits, part_all + 9 * PART_ITER16, cents1, csort_g, cnt_g, ofs_g, list_g);
    qg_kernel<<<NB * HB * CLN, 256, 0, stream>>>(q, cnt_g, ofs_g, list_g, qgf);
    scores_kernel<<<NB * HB * 32, 256, 0, stream>>>(k, qgf, keys);
    topsel_kernel<<<NB * HB * CLN, 256, 0, stream>>>(keys, tki_g);
    attn_quad_kernel<<<NQ / 16, 256, 0, stream>>>(q, k, v, list_g, csort_g, tki_g, out);
}

// Round 24
// 263.682 us; speedup vs baseline: 1.2808x; 1.2808x over previous
//
#include <hip/hip_runtime.h>
#include <math.h>

#define NB 2
#define HB 8
#define LB 2048
#define EB 64
#define BITSN 32
#define CLN 128
#define ITERS 10
#define TOPKN 32
#define NEGV -10000000.0f

typedef unsigned long long u64;
typedef unsigned int u32;

// u16-packed partials: part[nh][j*64 + c/2], fields (c even | c odd << 16),
// j = 0..31 bit-sums, j = 32 counts. All values <= 2048 -> no carry between
// fields under u32 atomicAdd (max field sum 4096 < 65536): exact.
#define PART_NH16 (33 * 64)                     // 2112 dwords per nh
#define PART_ITER16 (NB * HB * PART_NH16)       // 33792 dwords per iteration
#define PART_TOTAL16 (ITERS * PART_ITER16)      // 337920 dwords (~1.35 MB)
#define BITS_BLOCKS 4096                        // NQ/8
#define ZBLOCKS ((PART_TOTAL16 + 255) / 256)

// ---------------------------------------------------------------------------
// Kernel 1: LSH bits (blocks < BITS_BLOCKS) + zeroing of packed partials.
// ---------------------------------------------------------------------------
__global__ __launch_bounds__(256) void bits_zero_kernel(const float* __restrict__ q,
                                                        const float* __restrict__ planes,
                                                        u32* __restrict__ bits,
                                                        u32* __restrict__ zbuf) {
    int tid = threadIdx.x;
    int bid = blockIdx.x;
    if (bid >= BITS_BLOCKS) {
        int i = (bid - BITS_BLOCKS) * 256 + tid;
        if (i < PART_TOTAL16) zbuf[i] = 0u;
        return;
    }
    int wave = tid >> 6;
    int lane = tid & 63;
    int b = lane & 31;
    int which = lane >> 5;
    int qi = bid * 8 + wave * 2 + which;   // qi = (n*H + h)*L + l
    int l = qi & (LB - 1);
    int nh = qi / LB;
    int h = nh & (HB - 1);
    int n = nh / HB;
    const float* qrow = q + (((long long)n * LB + l) * HB + h) * EB;
    const float* prow = planes + b * (EB + 1);
    double acc = (double)prow[EB];                 // bias (the ones column)
    #pragma unroll 8
    for (int e = 0; e < EB; ++e) acc += (double)qrow[e] * (double)prow[e];
    unsigned long long m = __ballot(acc > 0.0);
    if (b == 0) {
        bits[qi] = (u32)(which ? (m >> 32) : (m & 0xffffffffULL));
    }
}

// ---------------------------------------------------------------------------
// K-means iteration: 128 blocks (16 nh x 8 tiles of 256 points), 256 thr.
// u16-packed partials; packed-key argmin (== first-min); per-set-bit LDS
// histogram of OWN 256 points; packed atomic dump (exact, deterministic).
// ---------------------------------------------------------------------------
__global__ __launch_bounds__(256) void kmeans_iter_kernel(const u32* __restrict__ bits,
                                                          const u32* __restrict__ part_prev,
                                                          u32* __restrict__ part_cur,
                                                          const u32* __restrict__ cent_prev_g,
                                                          u32* __restrict__ cent_cur_g,
                                                          int it) {
    __shared__ u32 cent[CLN];
    __shared__ int hist[33 * 128];       // unpacked [j*128+c]
    int tid = threadIdx.x;
    int bid = blockIdx.x;
    int nh = bid >> 3;
    int tile = bid & 7;
    int lane = tid & 63;

    for (int i = tid; i < 33 * 128; i += 256) hist[i] = 0;
    if (tid < CLN) {
        u32 cv;
        if (it == 0) {
            cv = bits[nh * LB + tid * (LB / CLN)];        // init_idx = 16c
        } else {
            const u32* pp = part_prev + nh * PART_NH16;
            int sh = (tid & 1) * 16;
            int cnt = (int)((pp[32 * 64 + (tid >> 1)] >> sh) & 0xffffu);
            u32 nb = 0u;
            #pragma unroll
            for (int j = 0; j < BITSN; ++j) {
                int s = (int)((pp[j * 64 + (tid >> 1)] >> sh) & 0xffffu);
                if (2 * s >= cnt) nb |= (1u << j);
            }
            cv = (cnt > 0) ? nb : cent_prev_g[nh * CLN + tid];
        }
        cent[tid] = cv;
        if (tile == 0) cent_cur_g[nh * CLN + tid] = cv;   // materialize chain
    }
    __syncthreads();

    int l = tile * 256 + tid;
    u32 bv = bits[nh * LB + l];

    // ---- argmin via packed key (d<<7)|c : min == first-min tie rule
    u32 clo = cent[lane], chi = cent[lane + 64];
    u32 best = 0x7fffffffu;
    #pragma unroll 16
    for (int c = 0; c < 64; ++c) {
        u32 cc = (u32)__builtin_amdgcn_readlane((int)clo, c);
        u32 key = ((u32)__popc(bv ^ cc) << 7) | (u32)c;
        best = (key < best) ? key : best;
    }
    #pragma unroll 16
    for (int c = 0; c < 64; ++c) {
        u32 cc = (u32)__builtin_amdgcn_readlane((int)chi, c);
        u32 key = ((u32)__popc(bv ^ cc) << 7) | (u32)(64 + c);
        best = (key < best) ? key : best;
    }
    int bc = (int)(best & 127u);

    // ---- per-set-bit LDS histogram (exact integer adds)
    atomicAdd(&hist[32 * 128 + bc], 1);
    u32 bb = bv;
    while (bb) { int j = __ffs(bb) - 1; atomicAdd(&hist[j * 128 + bc], 1); bb &= bb - 1; }
    __syncthreads();

    // ---- u16-packed dump (pair c=2p, 2p+1); skip zero pairs
    u32* pc = part_cur + nh * PART_NH16;
    for (int i = tid; i < PART_NH16; i += 256) {
        int j = i >> 6, p = i & 63;
        u32 v = (u32)hist[j * 128 + 2 * p] | ((u32)hist[j * 128 + 2 * p + 1] << 16);
        if (v) atomicAdd(&pc[i], v);
    }
}

// ---------------------------------------------------------------------------
// Kernel 3: final assignment + lists fused, 16 blocks x 1024 thr.
// ---------------------------------------------------------------------------
__global__ __launch_bounds__(1024) void list_final_kernel(const u32* __restrict__ bits,
                                                          const u32* __restrict__ part_prev,
                                                          const u32* __restrict__ cent_prev_g,
                                                          int* __restrict__ csort_g,
                                                          int* __restrict__ cnt_g,
                                                          int* __restrict__ ofs_g,
                                                          int* __restrict__ list_g) {
    __shared__ u32 cent[CLN];
    __shared__ int cnt[CLN];
    __shared__ int cntw[2][16][CLN];       // (group, wave, cluster)
    __shared__ int ofs[CLN];
    int nh = blockIdx.x;
    int tid = threadIdx.x;
    int w = tid >> 6, lane = tid & 63;

    if (tid < CLN) {
        const u32* pp = part_prev + nh * PART_NH16;
        int sh = (tid & 1) * 16;
        int cn = (int)((pp[32 * 64 + (tid >> 1)] >> sh) & 0xffffu);
        u32 nb = 0u;
        #pragma unroll
        for (int j = 0; j < BITSN; ++j) {
            int s = (int)((pp[j * 64 + (tid >> 1)] >> sh) & 0xffffu);
            if (2 * s >= cn) nb |= (1u << j);
        }
        cent[tid] = (cn > 0) ? nb : cent_prev_g[nh * CLN + tid];
        cnt[tid] = 0;
    }
    for (int i = tid; i < 2 * 16 * CLN; i += 1024) (&cntw[0][0][0])[i] = 0;
    __syncthreads();

    int l0 = tid, l1 = tid + 1024;
    u32 bv0 = bits[nh * LB + l0];
    u32 bv1 = bits[nh * LB + l1];
    u32 clo = cent[lane], chi = cent[lane + 64];
    u32 best0 = 0x7fffffffu, best1 = 0x7fffffffu;
    #pragma unroll 16
    for (int c = 0; c < 64; ++c) {
        u32 cc = (u32)__builtin_amdgcn_readlane((int)clo, c);
        u32 k0 = ((u32)__popc(bv0 ^ cc) << 7) | (u32)c;
        u32 k1 = ((u32)__popc(bv1 ^ cc) << 7) | (u32)c;
        best0 = (k0 < best0) ? k0 : best0;
        best1 = (k1 < best1) ? k1 : best1;
    }
    #pragma unroll 16
    for (int c = 0; c < 64; ++c) {
        u32 cc = (u32)__builtin_amdgcn_readlane((int)chi, c);
        u32 k0 = ((u32)__popc(bv0 ^ cc) << 7) | (u32)(64 + c);
        u32 k1 = ((u32)__popc(bv1 ^ cc) << 7) | (u32)(64 + c);
        best0 = (k0 < best0) ? k0 : best0;
        best1 = (k1 < best1) ? k1 : best1;
    }
    int bc0 = (int)(best0 & 127u);
    int bc1 = (int)(best1 & 127u);
    u64 ltmask = (lane == 0) ? 0ULL : (~0ULL >> (64 - lane));

    int rank0 = 0, rank1 = 0;
    for (int c = 0; c < CLN; ++c) {
        u64 m0 = __ballot(bc0 == c);
        u64 m1 = __ballot(bc1 == c);
        if ((m0 | m1) == 0ULL) continue;
        if (bc0 == c) rank0 = (int)__popcll(m0 & ltmask);
        if (bc1 == c) rank1 = (int)__popcll(m1 & ltmask);
        if (lane == 0) {
            int p0 = (int)__popcll(m0), p1 = (int)__popcll(m1);
            if (p0) cntw[0][w][c] = p0;
            if (p1) cntw[1][w][c] = p1;
            atomicAdd(&cnt[c], p0 + p1);
        }
    }
    __syncthreads();
    if (tid == 0) {
        int run = 0;
        for (int c = 0; c < CLN; ++c) { ofs[c] = run; run += cnt[c]; }
    }
    __syncthreads();
    if (tid < CLN) {           // absolute bases per (g,w) in ascending-l order
        int c = tid;
        int run = ofs[c];
        #pragma unroll
        for (int g = 0; g < 2; ++g)
            for (int ww = 0; ww < 16; ++ww) {
                int t = cntw[g][ww][c];
                cntw[g][ww][c] = run;
                run += t;
            }
        cnt_g[nh * CLN + c] = cnt[c];
        ofs_g[nh * CLN + c] = ofs[c];
    }
    __syncthreads();
    {
        int p0 = cntw[0][w][bc0] + rank0;
        int p1 = cntw[1][w][bc1] + rank1;
        list_g[nh * LB + p0] = l0;
        list_g[nh * LB + p1] = l1;
        csort_g[nh * LB + p0] = bc0;        // cluster id at list position
        csort_g[nh * LB + p1] = bc1;
    }
}

// ---------------------------------------------------------------------------
// Kernel 3b: Qg chip-wide. Block per (nh,c) x 4 waves; f64, fixed order.
// ---------------------------------------------------------------------------
__global__ __launch_bounds__(256) void qg_kernel(const float* __restrict__ q,
                                                 const int* __restrict__ cnt_g,
                                                 const int* __restrict__ ofs_g,
                                                 const int* __restrict__ list_g,
                                                 float* __restrict__ qgf) {
    __shared__ double ps[4][EB];
    int bid = blockIdx.x;            // nh*128 + c
    int nh = bid >> 7;
    int h = nh & (HB - 1);
    int n = nh / HB;
    int tid = threadIdx.x;
    int w = tid >> 6, lane = tid & 63;
    int cn = cnt_g[bid];
    int o = ofs_g[bid];
    const int* lp = list_g + nh * LB + o;
    double acc = 0.0;
    for (int i = w; i < cn; i += 4) {
        int l = lp[i];
        acc += (double)q[(((long long)n * LB + l) * HB + h) * EB + lane];
    }
    ps[w][lane] = acc;
    __syncthreads();
    if (tid < EB) {
        double s = ((ps[0][tid] + ps[1][tid]) + ps[2][tid]) + ps[3][tid];
        double dcn = (double)(cn > 0 ? cn : 1);
        qgf[(long long)bid * EB + tid] = (float)(s / dcn);
    }
}

// ---------------------------------------------------------------------------
// Kernel 4: scores with LDS-staged Qg (R20-verified). 512 blocks (nh x 32
// tiles of 64 rows) x 4 waves; block stages the nh's 32 KB Qg in LDS once;
// each wave holds 64 K rows in registers, 32-cluster slice, 4-way split
// accumulators (fixed combine). Coalesced key stores.
// ---------------------------------------------------------------------------
__global__ __launch_bounds__(256) void scores_kernel(const float* __restrict__ kk,
                                                     const float* __restrict__ qgf,
                                                     u32* __restrict__ keys) {
    __shared__ float qs[CLN * EB];   // 32 KB
    int bid = blockIdx.x;            // nh*32 + tile (64-row tiles)
    int nh = bid >> 5;
    int tile = bid & 31;
    int h = nh & (HB - 1);
    int n = nh / HB;
    int tid = threadIdx.x;
    int w = tid >> 6;
    int lane = tid & 63;
    int l = tile * 64 + lane;        // my row
    int cbase = w * 32;              // 32-cluster slice per wave

    // cooperative stage: 2048 float4 = 32 KB, coalesced
    {
        const float4* src = (const float4*)(qgf + (long long)nh * CLN * EB);
        float4* dst = (float4*)qs;
        #pragma unroll
        for (int i = 0; i < 8; ++i) dst[tid + 256 * i] = src[tid + 256 * i];
    }

    const float4* kr4 = (const float4*)(kk + (((long long)n * LB + l) * HB + h) * EB);
    float rr[EB];
    #pragma unroll
    for (int i = 0; i < 16; ++i) {
        float4 t4 = kr4[i];
        rr[4 * i] = t4.x; rr[4 * i + 1] = t4.y; rr[4 * i + 2] = t4.z; rr[4 * i + 3] = t4.w;
    }
    __syncthreads();

    for (int c = 0; c < 32; ++c) {
        const float4* qp = (const float4*)(qs + (cbase + c) * EB);  // LDS broadcast
        float a0 = 0.f, a1 = 0.f, a2 = 0.f, a3 = 0.f;
        #pragma unroll
        for (int i = 0; i < 4; ++i) {
            float4 q0 = qp[i], q1 = qp[4 + i], q2 = qp[8 + i], q3 = qp[12 + i];
            int e0 = 4 * i, e1 = 16 + 4 * i, e2 = 32 + 4 * i, e3 = 48 + 4 * i;
            a0 = fmaf(q0.x, rr[e0], a0); a0 = fmaf(q0.y, rr[e0 + 1], a0);
            a0 = fmaf(q0.z, rr[e0 + 2], a0); a0 = fmaf(q0.w, rr[e0 + 3], a0);
            a1 = fmaf(q1.x, rr[e1], a1); a1 = fmaf(q1.y, rr[e1 + 1], a1);
            a1 = fmaf(q1.z, rr[e1 + 2], a1); a1 = fmaf(q1.w, rr[e1 + 3], a1);
            a2 = fmaf(q2.x, rr[e2], a2); a2 = fmaf(q2.y, rr[e2 + 1], a2);
            a2 = fmaf(q2.z, rr[e2 + 2], a2); a2 = fmaf(q2.w, rr[e2 + 3], a2);
            a3 = fmaf(q3.x, rr[e3], a3); a3 = fmaf(q3.y, rr[e3 + 1], a3);
            a3 = fmaf(q3.z, rr[e3 + 2], a3); a3 = fmaf(q3.w, rr[e3 + 3], a3);
        }
        float acc = (a0 + a1) + (a2 + a3);   // fixed deterministic combine
        u32 u = __float_as_uint(acc);
        u = ((int)u < 0) ? ~u : (u | 0x80000000u);          // monotone f32->u32
        keys[((long long)(nh * CLN + cbase + c)) * LB + l] = u;
    }
}

// ---------------------------------------------------------------------------
// Kernel 5: top-32 per (n,h,c) via WARP-SORT register merge. One wave per
// block. Each lane bitonic-sorts its 32 packed keys (key<<32)|(2047-l)
// descending in registers; 6 shfl_xor merge levels keep top-32 of the union
// (classic bitonic top-k: max(m[i], partner m[31-i]) + 5-stage clean).
// Distinct u64 keys -> unique total order (value desc, index asc) ->
// bit-identical to the verified tournament's output.
// ---------------------------------------------------------------------------
__global__ __launch_bounds__(64) void topsel_kernel(const u32* __restrict__ keys,
                                                    int* __restrict__ tki_g) {
    int bid = blockIdx.x;            // nh*128 + c
    int lane = threadIdx.x;
    const uint4* kp4 = (const uint4*)(keys + (long long)bid * LB);
    u64 m[32];
    #pragma unroll
    for (int t = 0; t < 8; ++t) {
        uint4 kv = kp4[lane + 64 * t];
        int l0 = (lane + 64 * t) * 4;
        m[4 * t]     = ((u64)kv.x << 32) | (u32)(2047 - l0);
        m[4 * t + 1] = ((u64)kv.y << 32) | (u32)(2047 - (l0 + 1));
        m[4 * t + 2] = ((u64)kv.z << 32) | (u32)(2047 - (l0 + 2));
        m[4 * t + 3] = ((u64)kv.w << 32) | (u32)(2047 - (l0 + 3));
    }

    // ---- per-lane bitonic sort, descending (fully unrolled, registers)
    #pragma unroll
    for (int k = 2; k <= 32; k <<= 1) {
        #pragma unroll
        for (int j = k >> 1; j > 0; j >>= 1) {
            #pragma unroll
            for (int i = 0; i < 32; ++i) {
                int ixj = i ^ j;
                if (ixj > i) {
                    bool up = ((i & k) == 0);       // up-region: descending
                    u64 a = m[i], b = m[ixj];
                    if (up ? (a < b) : (a > b)) { m[i] = b; m[ixj] = a; }
                }
            }
        }
    }

    // ---- 6 cross-lane merge levels (keep top-32 of union each time)
    #pragma unroll
    for (int s = 1; s <= 32; s <<= 1) {
        #pragma unroll
        for (int i = 0; i < 16; ++i) {
            u64 pa = __shfl_xor(m[i], s);           // partner m[i]
            u64 pb = __shfl_xor(m[31 - i], s);      // partner m[31-i]
            u64 lo = m[i], hi = m[31 - i];
            m[i]      = (lo > pb) ? lo : pb;        // max(m[i], partner m[31-i])
            m[31 - i] = (hi > pa) ? hi : pa;        // max(m[31-i], partner m[i])
        }
        // clean: bitonic -> sorted descending (5 register stages)
        #pragma unroll
        for (int j = 16; j > 0; j >>= 1) {
            #pragma unroll
            for (int i = 0; i < 32; ++i) {
                if ((i & j) == 0) {
                    u64 a = m[i], b = m[i | j];
                    if (a < b) { m[i] = b; m[i | j] = a; }
                }
            }
        }
    }

    if (lane == 0) {
        #pragma unroll
        for (int r = 0; r < TOPKN; ++r)
            tki_g[bid * TOPKN + r] = 2047 - (int)(m[r] & 2047u);
    }
}

// ---------------------------------------------------------------------------
// Per-query attention body (R15-verified math, byte-identical semantics).
// ---------------------------------------------------------------------------
__device__ __forceinline__ void attn_one(const float* __restrict__ q,
                                         const float* __restrict__ kk,
                                         const float* __restrict__ vv,
                                         int n, int h, int l,
                                         const int* __restrict__ krow,
                                         int lane, float* __restrict__ out) {
    int j = lane & 31, p = lane >> 5;
    int kidx = krow[j];
    const float* vbase = vv + ((long long)n * LB * HB + h) * EB;
    float vreg[TOPKN];
    #pragma unroll
    for (int jj = 0; jj < TOPKN; ++jj) {
        int kj = __shfl(kidx, jj);
        vreg[jj] = vbase[(long long)kj * (HB * EB) + lane];
    }
    const float4* q4 = (const float4*)(q + (((long long)n * LB + l) * HB + h) * EB) + p * 8;
    const float4* k4 = (const float4*)(kk + (((long long)n * LB + kidx) * HB + h) * EB) + p * 8;
    float part = 0.f;
    #pragma unroll
    for (int i = 0; i < 8; ++i) {
        float4 a = q4[i], b = k4[i];
        part += a.x * b.x + a.y * b.y + a.z * b.z + a.w * b.w;
    }
    float qlo = __shfl(part, j);
    float qhi = __shfl(part, j + 32);
    float qk = qlo + qhi;
    bool future = kidx > l;
    float logit = 0.125f * (future ? NEGV : qk);
    float m = logit;
    #pragma unroll
    for (int off = 16; off; off >>= 1) m = fmaxf(m, __shfl_xor(m, off));
    float ex = expf(logit - m);
    float ssum = ex;
    #pragma unroll
    for (int off = 16; off; off >>= 1) ssum += __shfl_xor(ssum, off);
    float a = future ? 0.f : ex / ssum;
    float oacc = 0.f;
    #pragma unroll
    for (int jj = 0; jj < TOPKN; ++jj) {
        float aj = __shfl(a, jj);
        oacc = fmaf(aj, vreg[jj], oacc);
    }
    out[(((long long)n * LB + l) * HB + h) * EB + lane] = oacc;
}

// ---------------------------------------------------------------------------
// Shared-pair attention body (R17-verified shared path, byte-identical).
// ---------------------------------------------------------------------------
__device__ __forceinline__ void attn_pair_body(const float* __restrict__ q,
                                               const float* __restrict__ kk,
                                               const float* __restrict__ vv,
                                               int n, int h, int l0, int l1,
                                               const int* __restrict__ krow,
                                               int lane, float* __restrict__ out) {
    int j = lane & 31, p = lane >> 5;
    int kidx = krow[j];
    const float* vbase = vv + ((long long)n * LB * HB + h) * EB;
    float vreg[TOPKN];
    #pragma unroll
    for (int jj = 0; jj < TOPKN; ++jj) {
        int kj = __shfl(kidx, jj);
        vreg[jj] = vbase[(long long)kj * (HB * EB) + lane];
    }
    const float4* q40 = (const float4*)(q + (((long long)n * LB + l0) * HB + h) * EB) + p * 8;
    const float4* q41 = (const float4*)(q + (((long long)n * LB + l1) * HB + h) * EB) + p * 8;
    const float4* k4  = (const float4*)(kk + (((long long)n * LB + kidx) * HB + h) * EB) + p * 8;
    float part0 = 0.f, part1 = 0.f;
    #pragma unroll
    for (int i = 0; i < 8; ++i) {
        float4 b = k4[i];
        float4 a0 = q40[i], a1 = q41[i];
        part0 += a0.x * b.x + a0.y * b.y + a0.z * b.z + a0.w * b.w;
        part1 += a1.x * b.x + a1.y * b.y + a1.z * b.z + a1.w * b.w;
    }
    float qk0 = __shfl(part0, j) + __shfl(part0, j + 32);
    float qk1 = __shfl(part1, j) + __shfl(part1, j + 32);
    bool fut0 = kidx > l0, fut1 = kidx > l1;
    float lg0 = 0.125f * (fut0 ? NEGV : qk0);
    float lg1 = 0.125f * (fut1 ? NEGV : qk1);
    float m0 = lg0, m1 = lg1;
    #pragma unroll
    for (int off = 16; off; off >>= 1) {
        m0 = fmaxf(m0, __shfl_xor(m0, off));
        m1 = fmaxf(m1, __shfl_xor(m1, off));
    }
    float e0 = expf(lg0 - m0), e1 = expf(lg1 - m1);
    float s0 = e0, s1 = e1;
    #pragma unroll
    for (int off = 16; off; off >>= 1) {
        s0 += __shfl_xor(s0, off);
        s1 += __shfl_xor(s1, off);
    }
    float a0 = fut0 ? 0.f : e0 / s0;
    float a1 = fut1 ? 0.f : e1 / s1;
    float o0 = 0.f, o1 = 0.f;
    #pragma unroll
    for (int jj = 0; jj < TOPKN; ++jj) {
        float aj0 = __shfl(a0, jj);
        float aj1 = __shfl(a1, jj);
        o0 = fmaf(aj0, vreg[jj], o0);
        o1 = fmaf(aj1, vreg[jj], o1);
    }
    out[(((long long)n * LB + l0) * HB + h) * EB + lane] = o0;
    out[(((long long)n * LB + l1) * HB + h) * EB + lane] = o1;
}

// ---------------------------------------------------------------------------
// Kernel 6: QUAD gather attention in CLUSTER-SORTED order. All-same quads
// take the 4-way shared path; mixed quads decompose into per-half pair
// checks (pair shared path or attn_one x2). All branches wave-uniform;
// per-query math byte-identical to the verified kernels.
// ---------------------------------------------------------------------------
__global__ __launch_bounds__(256) void attn_quad_kernel(const float* __restrict__ q,
                                                        const float* __restrict__ kk,
                                                        const float* __restrict__ vv,
                                                        const int* __restrict__ list_g,
                                                        const int* __restrict__ csort_g,
                                                        const int* __restrict__ tki_g,
                                                        float* __restrict__ out) {
    int tid = threadIdx.x;
    int wave = tid >> 6, lane = tid & 63;
    int idx = blockIdx.x * 4 + wave;  // quad index: nh*(L/4) + qd
    int nh = idx >> 9;                // LB/4 = 512 quads per nh
    int qd = idx & 511;
    int pos = 4 * qd;
    int l0 = list_g[nh * LB + pos];
    int l1 = list_g[nh * LB + pos + 1];
    int l2 = list_g[nh * LB + pos + 2];
    int l3 = list_g[nh * LB + pos + 3];
    int c0 = csort_g[nh * LB + pos];
    int c1 = csort_g[nh * LB + pos + 1];
    int c2 = csort_g[nh * LB + pos + 2];
    int c3 = csort_g[nh * LB + pos + 3];
    int h = nh & (HB - 1);
    int n = nh / HB;

    if ((c0 != c1) | (c1 != c2) | (c2 != c3)) {   // wave-uniform decompose
        if (c0 == c1) {
            attn_pair_body(q, kk, vv, n, h, l0, l1, tki_g + (nh * CLN + c0) * TOPKN, lane, out);
        } else {
            attn_one(q, kk, vv, n, h, l0, tki_g + (nh * CLN + c0) * TOPKN, lane, out);
            attn_one(q, kk, vv, n, h, l1, tki_g + (nh * CLN + c1) * TOPKN, lane, out);
        }
        if (c2 == c3) {
            attn_pair_body(q, kk, vv, n, h, l2, l3, tki_g + (nh * CLN + c2) * TOPKN, lane, out);
        } else {
            attn_one(q, kk, vv, n, h, l2, tki_g + (nh * CLN + c2) * TOPKN, lane, out);
            attn_one(q, kk, vv, n, h, l3, tki_g + (nh * CLN + c3) * TOPKN, lane, out);
        }
        return;
    }

    // ---- shared path: one tki row, one V-preload, one K row set
    const int* krow = tki_g + (nh * CLN + c0) * TOPKN;
    int j = lane & 31, p = lane >> 5;
    int kidx = krow[j];
    const float* vbase = vv + ((long long)n * LB * HB + h) * EB;
    float vreg[TOPKN];
    #pragma unroll
    for (int jj = 0; jj < TOPKN; ++jj) {
        int kj = __shfl(kidx, jj);
        vreg[jj] = vbase[(long long)kj * (HB * EB) + lane];
    }

    const float4* q40 = (const float4*)(q + (((long long)n * LB + l0) * HB + h) * EB) + p * 8;
    const float4* q41 = (const float4*)(q + (((long long)n * LB + l1) * HB + h) * EB) + p * 8;
    const float4* q42 = (const float4*)(q + (((long long)n * LB + l2) * HB + h) * EB) + p * 8;
    const float4* q43 = (const float4*)(q + (((long long)n * LB + l3) * HB + h) * EB) + p * 8;
    const float4* k4  = (const float4*)(kk + (((long long)n * LB + kidx) * HB + h) * EB) + p * 8;
    float p0 = 0.f, p1 = 0.f, p2 = 0.f, p3 = 0.f;
    #pragma unroll
    for (int i = 0; i < 8; ++i) {
        float4 b = k4[i];
        float4 a0 = q40[i], a1 = q41[i], a2 = q42[i], a3 = q43[i];
        p0 += a0.x * b.x + a0.y * b.y + a0.z * b.z + a0.w * b.w;
        p1 += a1.x * b.x + a1.y * b.y + a1.z * b.z + a1.w * b.w;
        p2 += a2.x * b.x + a2.y * b.y + a2.z * b.z + a2.w * b.w;
        p3 += a3.x * b.x + a3.y * b.y + a3.z * b.z + a3.w * b.w;
    }
    float qk0 = __shfl(p0, j) + __shfl(p0, j + 32);
    float qk1 = __shfl(p1, j) + __shfl(p1, j + 32);
    float qk2 = __shfl(p2, j) + __shfl(p2, j + 32);
    float qk3 = __shfl(p3, j) + __shfl(p3, j + 32);

    bool f0 = kidx > l0, f1 = kidx > l1, f2 = kidx > l2, f3 = kidx > l3;
    float g0 = 0.125f * (f0 ? NEGV : qk0);
    float g1 = 0.125f * (f1 ? NEGV : qk1);
    float g2 = 0.125f * (f2 ? NEGV : qk2);
    float g3 = 0.125f * (f3 ? NEGV : qk3);
    float m0 = g0, m1 = g1, m2 = g2, m3 = g3;
    #pragma unroll
    for (int off = 16; off; off >>= 1) {
        m0 = fmaxf(m0, __shfl_xor(m0, off));
        m1 = fmaxf(m1, __shfl_xor(m1, off));
        m2 = fmaxf(m2, __shfl_xor(m2, off));
        m3 = fmaxf(m3, __shfl_xor(m3, off));
    }
    float e0 = expf(g0 - m0), e1 = expf(g1 - m1);
    float e2 = expf(g2 - m2), e3 = expf(g3 - m3);
    float s0 = e0, s1 = e1, s2 = e2, s3 = e3;
    #pragma unroll
    for (int off = 16; off; off >>= 1) {
        s0 += __shfl_xor(s0, off);
        s1 += __shfl_xor(s1, off);
        s2 += __shfl_xor(s2, off);
        s3 += __shfl_xor(s3, off);
    }
    float a0 = f0 ? 0.f : e0 / s0;
    float a1 = f1 ? 0.f : e1 / s1;
    float a2 = f2 ? 0.f : e2 / s2;
    float a3 = f3 ? 0.f : e3 / s3;

    float o0 = 0.f, o1 = 0.f, o2 = 0.f, o3 = 0.f;
    #pragma unroll
    for (int jj = 0; jj < TOPKN; ++jj) {
        float v = vreg[jj];
        o0 = fmaf(__shfl(a0, jj), v, o0);
        o1 = fmaf(__shfl(a1, jj), v, o1);
        o2 = fmaf(__shfl(a2, jj), v, o2);
        o3 = fmaf(__shfl(a3, jj), v, o3);
    }
    out[(((long long)n * LB + l0) * HB + h) * EB + lane] = o0;
    out[(((long long)n * LB + l1) * HB + h) * EB + lane] = o1;
    out[(((long long)n * LB + l2) * HB + h) * EB + lane] = o2;
    out[(((long long)n * LB + l3) * HB + h) * EB + lane] = o3;
}

// ---------------------------------------------------------------------------
extern "C" void kernel_launch(void* const* d_in, const int* in_sizes, int n_in,
                              void* d_out, int out_size, void* d_ws, size_t ws_size,
                              hipStream_t stream) {
    const float* q = (const float*)d_in[0];
    const float* k = (const float*)d_in[1];
    const float* v = (const float*)d_in[2];
    const float* planes = (const float*)d_in[3];
    float* out = (float*)d_out;

    const int NQ = NB * HB * LB;                  // 32768
    char* ws = (char*)d_ws;
    u32* bits     = (u32*)(ws);                    // 128 KB
    int* csort_g  = (int*)(ws + 0x20000);          // 128 KB (cluster per position)
    int* cnt_g    = (int*)(ws + 0x40000);          // 8 KB
    int* ofs_g    = (int*)(ws + 0x42000);          // 8 KB
    int* list_g   = (int*)(ws + 0x44000);          // 128 KB
    float* qgf    = (float*)(ws + 0x64000);        // 512 KB
    int* tki_g    = (int*)(ws + 0xE4000);          // 256 KB (2048 x 32 ints)
    u32* keys     = (u32*)(ws + 0x124000);         // 16 MB
    // clustering scratch ALIASES the keys region (dead once scores runs):
    u32* part_all = (u32*)(ws + 0x124000);         // 1.35 MB packed partials
    u32* cents0   = (u32*)(ws + 0x124000 + 0x180000);
    u32* cents1   = (u32*)(ws + 0x124000 + 0x182000);

    bits_zero_kernel<<<BITS_BLOCKS + ZBLOCKS, 256, 0, stream>>>(q, planes, bits, part_all);

    for (int it = 0; it < ITERS; ++it) {
        const u32* pp = part_all + (it == 0 ? 0 : (it - 1)) * PART_ITER16;
        u32* pc       = part_all + it * PART_ITER16;
        const u32* cprev = (it & 1) ? cents0 : cents1;   // cent_{it-1}
        u32* ccur        = (it & 1) ? cents1 : cents0;   // cent_it
        kmeans_iter_kernel<<<NB * HB * 8, 256, 0, stream>>>(bits, pp, pc, cprev, ccur, it);
    }
    // cent_10 from part[9] (carry cent_9, parity 1) + csort + lists
    list_final_kernel<<<NB * HB, 1024, 0, stream>>>(
        bits, part_all + 9 * PART_ITER16, cents1, csort_g, cnt_g, ofs_g, list_g);
    qg_kernel<<<NB * HB * CLN, 256, 0, stream>>>(q, cnt_g, ofs_g, list_g, qgf);
    scores_kernel<<<NB * HB * 32, 256, 0, stream>>>(k, qgf, keys);
    topsel_kernel<<<NB * HB * CLN, 64, 0, stream>>>(keys, tki_g);
    attn_quad_kernel<<<NQ / 16, 256, 0, stream>>>(q, k, v, list_g, csort_g, tki_g, out);
}

// Round 25
// 258.824 us; speedup vs baseline: 1.3049x; 1.0188x over previous
//
#include <hip/hip_runtime.h>
#include <math.h>

#define NB 2
#define HB 8
#define LB 2048
#define EB 64
#define BITSN 32
#define CLN 128
#define ITERS 10
#define TOPKN 32
#define NEGV -10000000.0f

typedef unsigned long long u64;
typedef unsigned int u32;

// u16-packed partials: part[nh][j*64 + c/2], fields (c even | c odd << 16),
// j = 0..31 bit-sums, j = 32 counts. All values <= 2048 -> no carry between
// fields under u32 atomicAdd (max field sum 4096 < 65536): exact.
#define PART_NH16 (33 * 64)                     // 2112 dwords per nh
#define PART_ITER16 (NB * HB * PART_NH16)       // 33792 dwords per iteration
#define PART_TOTAL16 (ITERS * PART_ITER16)      // 337920 dwords (~1.35 MB)
#define BITS_BLOCKS 4096                        // NQ/8
#define ZBLOCKS ((PART_TOTAL16 + 255) / 256)

// ---------------------------------------------------------------------------
// Kernel 1: LSH bits (blocks < BITS_BLOCKS) + zeroing of packed partials.
// ---------------------------------------------------------------------------
__global__ __launch_bounds__(256) void bits_zero_kernel(const float* __restrict__ q,
                                                        const float* __restrict__ planes,
                                                        u32* __restrict__ bits,
                                                        u32* __restrict__ zbuf) {
    int tid = threadIdx.x;
    int bid = blockIdx.x;
    if (bid >= BITS_BLOCKS) {
        int i = (bid - BITS_BLOCKS) * 256 + tid;
        if (i < PART_TOTAL16) zbuf[i] = 0u;
        return;
    }
    int wave = tid >> 6;
    int lane = tid & 63;
    int b = lane & 31;
    int which = lane >> 5;
    int qi = bid * 8 + wave * 2 + which;   // qi = (n*H + h)*L + l
    int l = qi & (LB - 1);
    int nh = qi / LB;
    int h = nh & (HB - 1);
    int n = nh / HB;
    const float* qrow = q + (((long long)n * LB + l) * HB + h) * EB;
    const float* prow = planes + b * (EB + 1);
    double acc = (double)prow[EB];                 // bias (the ones column)
    #pragma unroll 8
    for (int e = 0; e < EB; ++e) acc += (double)qrow[e] * (double)prow[e];
    unsigned long long m = __ballot(acc > 0.0);
    if (b == 0) {
        bits[qi] = (u32)(which ? (m >> 32) : (m & 0xffffffffULL));
    }
}

// ---------------------------------------------------------------------------
// K-means iteration: 128 blocks (16 nh x 8 tiles of 256 points), 256 thr.
// u16-packed partials; packed-key argmin (== first-min); per-set-bit LDS
// histogram of OWN 256 points; packed atomic dump (exact, deterministic).
// ---------------------------------------------------------------------------
__global__ __launch_bounds__(256) void kmeans_iter_kernel(const u32* __restrict__ bits,
                                                          const u32* __restrict__ part_prev,
                                                          u32* __restrict__ part_cur,
                                                          const u32* __restrict__ cent_prev_g,
                                                          u32* __restrict__ cent_cur_g,
                                                          int it) {
    __shared__ u32 cent[CLN];
    __shared__ int hist[33 * 128];       // unpacked [j*128+c]
    int tid = threadIdx.x;
    int bid = blockIdx.x;
    int nh = bid >> 3;
    int tile = bid & 7;
    int lane = tid & 63;

    for (int i = tid; i < 33 * 128; i += 256) hist[i] = 0;
    if (tid < CLN) {
        u32 cv;
        if (it == 0) {
            cv = bits[nh * LB + tid * (LB / CLN)];        // init_idx = 16c
        } else {
            const u32* pp = part_prev + nh * PART_NH16;
            int sh = (tid & 1) * 16;
            int cnt = (int)((pp[32 * 64 + (tid >> 1)] >> sh) & 0xffffu);
            u32 nb = 0u;
            #pragma unroll
            for (int j = 0; j < BITSN; ++j) {
                int s = (int)((pp[j * 64 + (tid >> 1)] >> sh) & 0xffffu);
                if (2 * s >= cnt) nb |= (1u << j);
            }
            cv = (cnt > 0) ? nb : cent_prev_g[nh * CLN + tid];
        }
        cent[tid] = cv;
        if (tile == 0) cent_cur_g[nh * CLN + tid] = cv;   // materialize chain
    }
    __syncthreads();

    int l = tile * 256 + tid;
    u32 bv = bits[nh * LB + l];

    // ---- argmin via packed key (d<<7)|c : min == first-min tie rule
    u32 clo = cent[lane], chi = cent[lane + 64];
    u32 best = 0x7fffffffu;
    #pragma unroll 16
    for (int c = 0; c < 64; ++c) {
        u32 cc = (u32)__builtin_amdgcn_readlane((int)clo, c);
        u32 key = ((u32)__popc(bv ^ cc) << 7) | (u32)c;
        best = (key < best) ? key : best;
    }
    #pragma unroll 16
    for (int c = 0; c < 64; ++c) {
        u32 cc = (u32)__builtin_amdgcn_readlane((int)chi, c);
        u32 key = ((u32)__popc(bv ^ cc) << 7) | (u32)(64 + c);
        best = (key < best) ? key : best;
    }
    int bc = (int)(best & 127u);

    // ---- per-set-bit LDS histogram (exact integer adds)
    atomicAdd(&hist[32 * 128 + bc], 1);
    u32 bb = bv;
    while (bb) { int j = __ffs(bb) - 1; atomicAdd(&hist[j * 128 + bc], 1); bb &= bb - 1; }
    __syncthreads();

    // ---- u16-packed dump (pair c=2p, 2p+1); skip zero pairs
    u32* pc = part_cur + nh * PART_NH16;
    for (int i = tid; i < PART_NH16; i += 256) {
        int j = i >> 6, p = i & 63;
        u32 v = (u32)hist[j * 128 + 2 * p] | ((u32)hist[j * 128 + 2 * p + 1] << 16);
        if (v) atomicAdd(&pc[i], v);
    }
}

// ---------------------------------------------------------------------------
// Kernel 3: final assignment + lists fused, 16 blocks x 1024 thr.
// ---------------------------------------------------------------------------
__global__ __launch_bounds__(1024) void list_final_kernel(const u32* __restrict__ bits,
                                                          const u32* __restrict__ part_prev,
                                                          const u32* __restrict__ cent_prev_g,
                                                          int* __restrict__ csort_g,
                                                          int* __restrict__ cnt_g,
                                                          int* __restrict__ ofs_g,
                                                          int* __restrict__ list_g) {
    __shared__ u32 cent[CLN];
    __shared__ int cnt[CLN];
    __shared__ int cntw[2][16][CLN];       // (group, wave, cluster)
    __shared__ int ofs[CLN];
    int nh = blockIdx.x;
    int tid = threadIdx.x;
    int w = tid >> 6, lane = tid & 63;

    if (tid < CLN) {
        const u32* pp = part_prev + nh * PART_NH16;
        int sh = (tid & 1) * 16;
        int cn = (int)((pp[32 * 64 + (tid >> 1)] >> sh) & 0xffffu);
        u32 nb = 0u;
        #pragma unroll
        for (int j = 0; j < BITSN; ++j) {
            int s = (int)((pp[j * 64 + (tid >> 1)] >> sh) & 0xffffu);
            if (2 * s >= cn) nb |= (1u << j);
        }
        cent[tid] = (cn > 0) ? nb : cent_prev_g[nh * CLN + tid];
        cnt[tid] = 0;
    }
    for (int i = tid; i < 2 * 16 * CLN; i += 1024) (&cntw[0][0][0])[i] = 0;
    __syncthreads();

    int l0 = tid, l1 = tid + 1024;
    u32 bv0 = bits[nh * LB + l0];
    u32 bv1 = bits[nh * LB + l1];
    u32 clo = cent[lane], chi = cent[lane + 64];
    u32 best0 = 0x7fffffffu, best1 = 0x7fffffffu;
    #pragma unroll 16
    for (int c = 0; c < 64; ++c) {
        u32 cc = (u32)__builtin_amdgcn_readlane((int)clo, c);
        u32 k0 = ((u32)__popc(bv0 ^ cc) << 7) | (u32)c;
        u32 k1 = ((u32)__popc(bv1 ^ cc) << 7) | (u32)c;
        best0 = (k0 < best0) ? k0 : best0;
        best1 = (k1 < best1) ? k1 : best1;
    }
    #pragma unroll 16
    for (int c = 0; c < 64; ++c) {
        u32 cc = (u32)__builtin_amdgcn_readlane((int)chi, c);
        u32 k0 = ((u32)__popc(bv0 ^ cc) << 7) | (u32)(64 + c);
        u32 k1 = ((u32)__popc(bv1 ^ cc) << 7) | (u32)(64 + c);
        best0 = (k0 < best0) ? k0 : best0;
        best1 = (k1 < best1) ? k1 : best1;
    }
    int bc0 = (int)(best0 & 127u);
    int bc1 = (int)(best1 & 127u);
    u64 ltmask = (lane == 0) ? 0ULL : (~0ULL >> (64 - lane));

    int rank0 = 0, rank1 = 0;
    for (int c = 0; c < CLN; ++c) {
        u64 m0 = __ballot(bc0 == c);
        u64 m1 = __ballot(bc1 == c);
        if ((m0 | m1) == 0ULL) continue;
        if (bc0 == c) rank0 = (int)__popcll(m0 & ltmask);
        if (bc1 == c) rank1 = (int)__popcll(m1 & ltmask);
        if (lane == 0) {
            int p0 = (int)__popcll(m0), p1 = (int)__popcll(m1);
            if (p0) cntw[0][w][c] = p0;
            if (p1) cntw[1][w][c] = p1;
            atomicAdd(&cnt[c], p0 + p1);
        }
    }
    __syncthreads();
    if (tid == 0) {
        int run = 0;
        for (int c = 0; c < CLN; ++c) { ofs[c] = run; run += cnt[c]; }
    }
    __syncthreads();
    if (tid < CLN) {           // absolute bases per (g,w) in ascending-l order
        int c = tid;
        int run = ofs[c];
        #pragma unroll
        for (int g = 0; g < 2; ++g)
            for (int ww = 0; ww < 16; ++ww) {
                int t = cntw[g][ww][c];
                cntw[g][ww][c] = run;
                run += t;
            }
        cnt_g[nh * CLN + c] = cnt[c];
        ofs_g[nh * CLN + c] = ofs[c];
    }
    __syncthreads();
    {
        int p0 = cntw[0][w][bc0] + rank0;
        int p1 = cntw[1][w][bc1] + rank1;
        list_g[nh * LB + p0] = l0;
        list_g[nh * LB + p1] = l1;
        csort_g[nh * LB + p0] = bc0;        // cluster id at list position
        csort_g[nh * LB + p1] = bc1;
    }
}

// ---------------------------------------------------------------------------
// Kernel 3b: Qg chip-wide. Block per (nh,c) x 4 waves; f64, fixed order.
// ---------------------------------------------------------------------------
__global__ __launch_bounds__(256) void qg_kernel(const float* __restrict__ q,
                                                 const int* __restrict__ cnt_g,
                                                 const int* __restrict__ ofs_g,
                                                 const int* __restrict__ list_g,
                                                 float* __restrict__ qgf) {
    __shared__ double ps[4][EB];
    int bid = blockIdx.x;            // nh*128 + c
    int nh = bid >> 7;
    int h = nh & (HB - 1);
    int n = nh / HB;
    int tid = threadIdx.x;
    int w = tid >> 6, lane = tid & 63;
    int cn = cnt_g[bid];
    int o = ofs_g[bid];
    const int* lp = list_g + nh * LB + o;
    double acc = 0.0;
    for (int i = w; i < cn; i += 4) {
        int l = lp[i];
        acc += (double)q[(((long long)n * LB + l) * HB + h) * EB + lane];
    }
    ps[w][lane] = acc;
    __syncthreads();
    if (tid < EB) {
        double s = ((ps[0][tid] + ps[1][tid]) + ps[2][tid]) + ps[3][tid];
        double dcn = (double)(cn > 0 ? cn : 1);
        qgf[(long long)bid * EB + tid] = (float)(s / dcn);
    }
}

// ---------------------------------------------------------------------------
// Kernel 4: scores with LDS-staged Qg (R20-verified). 512 blocks (nh x 32
// tiles of 64 rows) x 4 waves; block stages the nh's 32 KB Qg in LDS once;
// each wave holds 64 K rows in registers, 32-cluster slice, 4-way split
// accumulators (fixed combine). Coalesced key stores.
// ---------------------------------------------------------------------------
__global__ __launch_bounds__(256) void scores_kernel(const float* __restrict__ kk,
                                                     const float* __restrict__ qgf,
                                                     u32* __restrict__ keys) {
    __shared__ float qs[CLN * EB];   // 32 KB
    int bid = blockIdx.x;            // nh*32 + tile (64-row tiles)
    int nh = bid >> 5;
    int tile = bid & 31;
    int h = nh & (HB - 1);
    int n = nh / HB;
    int tid = threadIdx.x;
    int w = tid >> 6;
    int lane = tid & 63;
    int l = tile * 64 + lane;        // my row
    int cbase = w * 32;              // 32-cluster slice per wave

    // cooperative stage: 2048 float4 = 32 KB, coalesced
    {
        const float4* src = (const float4*)(qgf + (long long)nh * CLN * EB);
        float4* dst = (float4*)qs;
        #pragma unroll
        for (int i = 0; i < 8; ++i) dst[tid + 256 * i] = src[tid + 256 * i];
    }

    const float4* kr4 = (const float4*)(kk + (((long long)n * LB + l) * HB + h) * EB);
    float rr[EB];
    #pragma unroll
    for (int i = 0; i < 16; ++i) {
        float4 t4 = kr4[i];
        rr[4 * i] = t4.x; rr[4 * i + 1] = t4.y; rr[4 * i + 2] = t4.z; rr[4 * i + 3] = t4.w;
    }
    __syncthreads();

    for (int c = 0; c < 32; ++c) {
        const float4* qp = (const float4*)(qs + (cbase + c) * EB);  // LDS broadcast
        float a0 = 0.f, a1 = 0.f, a2 = 0.f, a3 = 0.f;
        #pragma unroll
        for (int i = 0; i < 4; ++i) {
            float4 q0 = qp[i], q1 = qp[4 + i], q2 = qp[8 + i], q3 = qp[12 + i];
            int e0 = 4 * i, e1 = 16 + 4 * i, e2 = 32 + 4 * i, e3 = 48 + 4 * i;
            a0 = fmaf(q0.x, rr[e0], a0); a0 = fmaf(q0.y, rr[e0 + 1], a0);
            a0 = fmaf(q0.z, rr[e0 + 2], a0); a0 = fmaf(q0.w, rr[e0 + 3], a0);
            a1 = fmaf(q1.x, rr[e1], a1); a1 = fmaf(q1.y, rr[e1 + 1], a1);
            a1 = fmaf(q1.z, rr[e1 + 2], a1); a1 = fmaf(q1.w, rr[e1 + 3], a1);
            a2 = fmaf(q2.x, rr[e2], a2); a2 = fmaf(q2.y, rr[e2 + 1], a2);
            a2 = fmaf(q2.z, rr[e2 + 2], a2); a2 = fmaf(q2.w, rr[e2 + 3], a2);
            a3 = fmaf(q3.x, rr[e3], a3); a3 = fmaf(q3.y, rr[e3 + 1], a3);
            a3 = fmaf(q3.z, rr[e3 + 2], a3); a3 = fmaf(q3.w, rr[e3 + 3], a3);
        }
        float acc = (a0 + a1) + (a2 + a3);   // fixed deterministic combine
        u32 u = __float_as_uint(acc);
        u = ((int)u < 0) ? ~u : (u | 0x80000000u);          // monotone f32->u32
        keys[((long long)(nh * CLN + cbase + c)) * LB + l] = u;
    }
}

// ---------------------------------------------------------------------------
// Kernel 5: top-32 per (n,h,c), HIERARCHICAL tournament. One 256-thr block
// per cluster. Phase 1: wave w tournaments its 512-key quarter (8 keys/lane,
// rescan chain 8 deep) -> its top-32 (descending) to LDS. Phase 2: wave 0
// tournaments the 128 candidates (2/lane). Union of quarter top-32s contains
// the global top-32; distinct packed keys (key<<32)|(2047-l) give a unique
// total order (value desc, index asc) -> bit-identical to the verified
// single-wave tournament.
// ---------------------------------------------------------------------------
__global__ __launch_bounds__(256) void topsel_kernel(const u32* __restrict__ keys,
                                                     int* __restrict__ tki_g) {
    __shared__ u64 cand[128];        // 4 waves x 32 winners
    int bid = blockIdx.x;            // nh*128 + c
    int tid = threadIdx.x;
    int w = tid >> 6, lane = tid & 63;

    // ---- phase 1: wave w over keys [w*512, w*512+512)
    {
        const uint4* kp4 = (const uint4*)(keys + (long long)bid * LB);
        u64 k[8];
        #pragma unroll
        for (int t = 0; t < 2; ++t) {
            int qi = w * 128 + lane + 64 * t;     // uint4 index
            uint4 kv = kp4[qi];
            int l0 = qi * 4;
            k[4 * t]     = ((u64)kv.x << 32) | (u32)(2047 - l0);
            k[4 * t + 1] = ((u64)kv.y << 32) | (u32)(2047 - (l0 + 1));
            k[4 * t + 2] = ((u64)kv.z << 32) | (u32)(2047 - (l0 + 2));
            k[4 * t + 3] = ((u64)kv.w << 32) | (u32)(2047 - (l0 + 3));
        }
        u64 m0 = k[0], m1 = k[4];
        #pragma unroll
        for (int t = 1; t < 4; ++t) {
            if (k[t] > m0) m0 = k[t];
            if (k[4 + t] > m1) m1 = k[4 + t];
        }
        u64 cur = (m1 > m0) ? m1 : m0;

        for (int r = 0; r < TOPKN; ++r) {
            u64 wk = cur;
            #pragma unroll
            for (int off = 1; off < 64; off <<= 1) {
                u64 o = __shfl_xor(wk, off);
                if (o > wk) wk = o;
            }
            if (lane == 0) cand[w * TOPKN + r] = wk;
            if (wk == cur) {               // unique owner: implicit-delete rescan
                u64 nm = 0ULL;
                #pragma unroll
                for (int t = 0; t < 8; ++t) {
                    u64 kt = k[t];
                    u64 c2 = (kt < wk) ? kt : 0ULL;
                    if (c2 > nm) nm = c2;
                }
                cur = nm;
            }
        }
    }
    __syncthreads();

    // ---- phase 2: wave 0 over the 128 candidates (2 per lane)
    if (w == 0) {
        u64 k0 = cand[lane], k1 = cand[lane + 64];
        u64 cur = (k0 > k1) ? k0 : k1;
        for (int r = 0; r < TOPKN; ++r) {
            u64 wk = cur;
            #pragma unroll
            for (int off = 1; off < 64; off <<= 1) {
                u64 o = __shfl_xor(wk, off);
                if (o > wk) wk = o;
            }
            if (lane == 0) tki_g[bid * TOPKN + r] = 2047 - (int)(wk & 2047u);
            if (wk == cur) {
                u64 a = (k0 < wk) ? k0 : 0ULL;
                u64 b = (k1 < wk) ? k1 : 0ULL;
                cur = (a > b) ? a : b;
            }
        }
    }
}

// ---------------------------------------------------------------------------
// Per-query attention body (R15-verified math, byte-identical semantics).
// ---------------------------------------------------------------------------
__device__ __forceinline__ void attn_one(const float* __restrict__ q,
                                         const float* __restrict__ kk,
                                         const float* __restrict__ vv,
                                         int n, int h, int l,
                                         const int* __restrict__ krow,
                                         int lane, float* __restrict__ out) {
    int j = lane & 31, p = lane >> 5;
    int kidx = krow[j];
    const float* vbase = vv + ((long long)n * LB * HB + h) * EB;
    float vreg[TOPKN];
    #pragma unroll
    for (int jj = 0; jj < TOPKN; ++jj) {
        int kj = __shfl(kidx, jj);
        vreg[jj] = vbase[(long long)kj * (HB * EB) + lane];
    }
    const float4* q4 = (const float4*)(q + (((long long)n * LB + l) * HB + h) * EB) + p * 8;
    const float4* k4 = (const float4*)(kk + (((long long)n * LB + kidx) * HB + h) * EB) + p * 8;
    float part = 0.f;
    #pragma unroll
    for (int i = 0; i < 8; ++i) {
        float4 a = q4[i], b = k4[i];
        part += a.x * b.x + a.y * b.y + a.z * b.z + a.w * b.w;
    }
    float qlo = __shfl(part, j);
    float qhi = __shfl(part, j + 32);
    float qk = qlo + qhi;
    bool future = kidx > l;
    float logit = 0.125f * (future ? NEGV : qk);
    float m = logit;
    #pragma unroll
    for (int off = 16; off; off >>= 1) m = fmaxf(m, __shfl_xor(m, off));
    float ex = expf(logit - m);
    float ssum = ex;
    #pragma unroll
    for (int off = 16; off; off >>= 1) ssum += __shfl_xor(ssum, off);
    float a = future ? 0.f : ex / ssum;
    float oacc = 0.f;
    #pragma unroll
    for (int jj = 0; jj < TOPKN; ++jj) {
        float aj = __shfl(a, jj);
        oacc = fmaf(aj, vreg[jj], oacc);
    }
    out[(((long long)n * LB + l) * HB + h) * EB + lane] = oacc;
}

// ---------------------------------------------------------------------------
// Shared-pair attention body (R17-verified shared path, byte-identical).
// ---------------------------------------------------------------------------
__device__ __forceinline__ void attn_pair_body(const float* __restrict__ q,
                                               const float* __restrict__ kk,
                                               const float* __restrict__ vv,
                                               int n, int h, int l0, int l1,
                                               const int* __restrict__ krow,
                                               int lane, float* __restrict__ out) {
    int j = lane & 31, p = lane >> 5;
    int kidx = krow[j];
    const float* vbase = vv + ((long long)n * LB * HB + h) * EB;
    float vreg[TOPKN];
    #pragma unroll
    for (int jj = 0; jj < TOPKN; ++jj) {
        int kj = __shfl(kidx, jj);
        vreg[jj] = vbase[(long long)kj * (HB * EB) + lane];
    }
    const float4* q40 = (const float4*)(q + (((long long)n * LB + l0) * HB + h) * EB) + p * 8;
    const float4* q41 = (const float4*)(q + (((long long)n * LB + l1) * HB + h) * EB) + p * 8;
    const float4* k4  = (const float4*)(kk + (((long long)n * LB + kidx) * HB + h) * EB) + p * 8;
    float part0 = 0.f, part1 = 0.f;
    #pragma unroll
    for (int i = 0; i < 8; ++i) {
        float4 b = k4[i];
        float4 a0 = q40[i], a1 = q41[i];
        part0 += a0.x * b.x + a0.y * b.y + a0.z * b.z + a0.w * b.w;
        part1 += a1.x * b.x + a1.y * b.y + a1.z * b.z + a1.w * b.w;
    }
    float qk0 = __shfl(part0, j) + __shfl(part0, j + 32);
    float qk1 = __shfl(part1, j) + __shfl(part1, j + 32);
    bool fut0 = kidx > l0, fut1 = kidx > l1;
    float lg0 = 0.125f * (fut0 ? NEGV : qk0);
    float lg1 = 0.125f * (fut1 ? NEGV : qk1);
    float m0 = lg0, m1 = lg1;
    #pragma unroll
    for (int off = 16; off; off >>= 1) {
        m0 = fmaxf(m0, __shfl_xor(m0, off));
        m1 = fmaxf(m1, __shfl_xor(m1, off));
    }
    float e0 = expf(lg0 - m0), e1 = expf(lg1 - m1);
    float s0 = e0, s1 = e1;
    #pragma unroll
    for (int off = 16; off; off >>= 1) {
        s0 += __shfl_xor(s0, off);
        s1 += __shfl_xor(s1, off);
    }
    float a0 = fut0 ? 0.f : e0 / s0;
    float a1 = fut1 ? 0.f : e1 / s1;
    float o0 = 0.f, o1 = 0.f;
    #pragma unroll
    for (int jj = 0; jj < TOPKN; ++jj) {
        float aj0 = __shfl(a0, jj);
        float aj1 = __shfl(a1, jj);
        o0 = fmaf(aj0, vreg[jj], o0);
        o1 = fmaf(aj1, vreg[jj], o1);
    }
    out[(((long long)n * LB + l0) * HB + h) * EB + lane] = o0;
    out[(((long long)n * LB + l1) * HB + h) * EB + lane] = o1;
}

// ---------------------------------------------------------------------------
// Kernel 6: QUAD gather attention in CLUSTER-SORTED order. All-same quads
// take the 4-way shared path; mixed quads decompose into per-half pair
// checks (pair shared path or attn_one x2). All branches wave-uniform;
// per-query math byte-identical to the verified kernels.
// ---------------------------------------------------------------------------
__global__ __launch_bounds__(256) void attn_quad_kernel(const float* __restrict__ q,
                                                        const float* __restrict__ kk,
                                                        const float* __restrict__ vv,
                                                        const int* __restrict__ list_g,
                                                        const int* __restrict__ csort_g,
                                                        const int* __restrict__ tki_g,
                                                        float* __restrict__ out) {
    int tid = threadIdx.x;
    int wave = tid >> 6, lane = tid & 63;
    int idx = blockIdx.x * 4 + wave;  // quad index: nh*(L/4) + qd
    int nh = idx >> 9;                // LB/4 = 512 quads per nh
    int qd = idx & 511;
    int pos = 4 * qd;
    int l0 = list_g[nh * LB + pos];
    int l1 = list_g[nh * LB + pos + 1];
    int l2 = list_g[nh * LB + pos + 2];
    int l3 = list_g[nh * LB + pos + 3];
    int c0 = csort_g[nh * LB + pos];
    int c1 = csort_g[nh * LB + pos + 1];
    int c2 = csort_g[nh * LB + pos + 2];
    int c3 = csort_g[nh * LB + pos + 3];
    int h = nh & (HB - 1);
    int n = nh / HB;

    if ((c0 != c1) | (c1 != c2) | (c2 != c3)) {   // wave-uniform decompose
        if (c0 == c1) {
            attn_pair_body(q, kk, vv, n, h, l0, l1, tki_g + (nh * CLN + c0) * TOPKN, lane, out);
        } else {
            attn_one(q, kk, vv, n, h, l0, tki_g + (nh * CLN + c0) * TOPKN, lane, out);
            attn_one(q, kk, vv, n, h, l1, tki_g + (nh * CLN + c1) * TOPKN, lane, out);
        }
        if (c2 == c3) {
            attn_pair_body(q, kk, vv, n, h, l2, l3, tki_g + (nh * CLN + c2) * TOPKN, lane, out);
        } else {
            attn_one(q, kk, vv, n, h, l2, tki_g + (nh * CLN + c2) * TOPKN, lane, out);
            attn_one(q, kk, vv, n, h, l3, tki_g + (nh * CLN + c3) * TOPKN, lane, out);
        }
        return;
    }

    // ---- shared path: one tki row, one V-preload, one K row set
    const int* krow = tki_g + (nh * CLN + c0) * TOPKN;
    int j = lane & 31, p = lane >> 5;
    int kidx = krow[j];
    const float* vbase = vv + ((long long)n * LB * HB + h) * EB;
    float vreg[TOPKN];
    #pragma unroll
    for (int jj = 0; jj < TOPKN; ++jj) {
        int kj = __shfl(kidx, jj);
        vreg[jj] = vbase[(long long)kj * (HB * EB) + lane];
    }

    const float4* q40 = (const float4*)(q + (((long long)n * LB + l0) * HB + h) * EB) + p * 8;
    const float4* q41 = (const float4*)(q + (((long long)n * LB + l1) * HB + h) * EB) + p * 8;
    const float4* q42 = (const float4*)(q + (((long long)n * LB + l2) * HB + h) * EB) + p * 8;
    const float4* q43 = (const float4*)(q + (((long long)n * LB + l3) * HB + h) * EB) + p * 8;
    const float4* k4  = (const float4*)(kk + (((long long)n * LB + kidx) * HB + h) * EB) + p * 8;
    float p0 = 0.f, p1 = 0.f, p2 = 0.f, p3 = 0.f;
    #pragma unroll
    for (int i = 0; i < 8; ++i) {
        float4 b = k4[i];
        float4 a0 = q40[i], a1 = q41[i], a2 = q42[i], a3 = q43[i];
        p0 += a0.x * b.x + a0.y * b.y + a0.z * b.z + a0.w * b.w;
        p1 += a1.x * b.x + a1.y * b.y + a1.z * b.z + a1.w * b.w;
        p2 += a2.x * b.x + a2.y * b.y + a2.z * b.z + a2.w * b.w;
        p3 += a3.x * b.x + a3.y * b.y + a3.z * b.z + a3.w * b.w;
    }
    float qk0 = __shfl(p0, j) + __shfl(p0, j + 32);
    float qk1 = __shfl(p1, j) + __shfl(p1, j + 32);
    float qk2 = __shfl(p2, j) + __shfl(p2, j + 32);
    float qk3 = __shfl(p3, j) + __shfl(p3, j + 32);

    bool f0 = kidx > l0, f1 = kidx > l1, f2 = kidx > l2, f3 = kidx > l3;
    float g0 = 0.125f * (f0 ? NEGV : qk0);
    float g1 = 0.125f * (f1 ? NEGV : qk1);
    float g2 = 0.125f * (f2 ? NEGV : qk2);
    float g3 = 0.125f * (f3 ? NEGV : qk3);
    float m0 = g0, m1 = g1, m2 = g2, m3 = g3;
    #pragma unroll
    for (int off = 16; off; off >>= 1) {
        m0 = fmaxf(m0, __shfl_xor(m0, off));
        m1 = fmaxf(m1, __shfl_xor(m1, off));
        m2 = fmaxf(m2, __shfl_xor(m2, off));
        m3 = fmaxf(m3, __shfl_xor(m3, off));
    }
    float e0 = expf(g0 - m0), e1 = expf(g1 - m1);
    float e2 = expf(g2 - m2), e3 = expf(g3 - m3);
    float s0 = e0, s1 = e1, s2 = e2, s3 = e3;
    #pragma unroll
    for (int off = 16; off; off >>= 1) {
        s0 += __shfl_xor(s0, off);
        s1 += __shfl_xor(s1, off);
        s2 += __shfl_xor(s2, off);
        s3 += __shfl_xor(s3, off);
    }
    float a0 = f0 ? 0.f : e0 / s0;
    float a1 = f1 ? 0.f : e1 / s1;
    float a2 = f2 ? 0.f : e2 / s2;
    float a3 = f3 ? 0.f : e3 / s3;

    float o0 = 0.f, o1 = 0.f, o2 = 0.f, o3 = 0.f;
    #pragma unroll
    for (int jj = 0; jj < TOPKN; ++jj) {
        float v = vreg[jj];
        o0 = fmaf(__shfl(a0, jj), v, o0);
        o1 = fmaf(__shfl(a1, jj), v, o1);
        o2 = fmaf(__shfl(a2, jj), v, o2);
        o3 = fmaf(__shfl(a3, jj), v, o3);
    }
    out[(((long long)n * LB + l0) * HB + h) * EB + lane] = o0;
    out[(((long long)n * LB + l1) * HB + h) * EB + lane] = o1;
    out[(((long long)n * LB + l2) * HB + h) * EB + lane] = o2;
    out[(((long long)n * LB + l3) * HB + h) * EB + lane] = o3;
}

// ---------------------------------------------------------------------------
extern "C" void kernel_launch(void* const* d_in, const int* in_sizes, int n_in,
                              void* d_out, int out_size, void* d_ws, size_t ws_size,
                              hipStream_t stream) {
    const float* q = (const float*)d_in[0];
    const float* k = (const float*)d_in[1];
    const float* v = (const float*)d_in[2];
    const float* planes = (const float*)d_in[3];
    float* out = (float*)d_out;

    const int NQ = NB * HB * LB;                  // 32768
    char* ws = (char*)d_ws;
    u32* bits     = (u32*)(ws);                    // 128 KB
    int* csort_g  = (int*)(ws + 0x20000);          // 128 KB (cluster per position)
    int* cnt_g    = (int*)(ws + 0x40000);          // 8 KB
    int* ofs_g    = (int*)(ws + 0x42000);          // 8 KB
    int* list_g   = (int*)(ws + 0x44000);          // 128 KB
    float* qgf    = (float*)(ws + 0x64000);        // 512 KB
    int* tki_g    = (int*)(ws + 0xE4000);          // 256 KB (2048 x 32 ints)
    u32* keys     = (u32*)(ws + 0x124000);         // 16 MB
    // clustering scratch ALIASES the keys region (dead once scores runs):
    u32* part_all = (u32*)(ws + 0x124000);         // 1.35 MB packed partials
    u32* cents0   = (u32*)(ws + 0x124000 + 0x180000);
    u32* cents1   = (u32*)(ws + 0x124000 + 0x182000);

    bits_zero_kernel<<<BITS_BLOCKS + ZBLOCKS, 256, 0, stream>>>(q, planes, bits, part_all);

    for (int it = 0; it < ITERS; ++it) {
        const u32* pp = part_all + (it == 0 ? 0 : (it - 1)) * PART_ITER16;
        u32* pc       = part_all + it * PART_ITER16;
        const u32* cprev = (it & 1) ? cents0 : cents1;   // cent_{it-1}
        u32* ccur        = (it & 1) ? cents1 : cents0;   // cent_it
        kmeans_iter_kernel<<<NB * HB * 8, 256, 0, stream>>>(bits, pp, pc, cprev, ccur, it);
    }
    // cent_10 from part[9] (carry cent_9, parity 1) + csort + lists
    list_final_kernel<<<NB * HB, 1024, 0, stream>>>(
        bits, part_all + 9 * PART_ITER16, cents1, csort_g, cnt_g, ofs_g, list_g);
    qg_kernel<<<NB * HB * CLN, 256, 0, stream>>>(q, cnt_g, ofs_g, list_g, qgf);
    scores_kernel<<<NB * HB * 32, 256, 0, stream>>>(k, qgf, keys);
    topsel_kernel<<<NB * HB * CLN, 256, 0, stream>>>(keys, tki_g);
    attn_quad_kernel<<<NQ / 16, 256, 0, stream>>>(q, k, v, list_g, csort_g, tki_g, out);
}

// Round 26
// 243.050 us; speedup vs baseline: 1.3896x; 1.0649x over previous
//
#include <hip/hip_runtime.h>
#include <math.h>

#define NB 2
#define HB 8
#define LB 2048
#define EB 64
#define BITSN 32
#define CLN 128
#define ITERS 10
#define TOPKN 32
#define NEGV -10000000.0f

typedef unsigned long long u64;
typedef unsigned int u32;

// u16-packed partials: part[nh][j*64 + c/2], fields (c even | c odd << 16),
// j = 0..31 bit-sums, j = 32 counts. All values <= 2048 -> no carry between
// fields under u32 atomicAdd (max field sum 4096 < 65536): exact.
#define PART_NH16 (33 * 64)                     // 2112 dwords per nh
#define PART_ITER16 (NB * HB * PART_NH16)       // 33792 dwords per iteration
#define PART_TOTAL16 (ITERS * PART_ITER16)      // 337920 dwords (~1.35 MB)
#define BITS_BLOCKS 4096                        // NQ/8
#define ZBLOCKS ((PART_TOTAL16 + 255) / 256)

// ---------------------------------------------------------------------------
// Kernel 1: LSH bits (blocks < BITS_BLOCKS) + zeroing of packed partials.
// ---------------------------------------------------------------------------
__global__ __launch_bounds__(256) void bits_zero_kernel(const float* __restrict__ q,
                                                        const float* __restrict__ planes,
                                                        u32* __restrict__ bits,
                                                        u32* __restrict__ zbuf) {
    int tid = threadIdx.x;
    int bid = blockIdx.x;
    if (bid >= BITS_BLOCKS) {
        int i = (bid - BITS_BLOCKS) * 256 + tid;
        if (i < PART_TOTAL16) zbuf[i] = 0u;
        return;
    }
    int wave = tid >> 6;
    int lane = tid & 63;
    int b = lane & 31;
    int which = lane >> 5;
    int qi = bid * 8 + wave * 2 + which;   // qi = (n*H + h)*L + l
    int l = qi & (LB - 1);
    int nh = qi / LB;
    int h = nh & (HB - 1);
    int n = nh / HB;
    const float* qrow = q + (((long long)n * LB + l) * HB + h) * EB;
    const float* prow = planes + b * (EB + 1);
    double acc = (double)prow[EB];                 // bias (the ones column)
    #pragma unroll 8
    for (int e = 0; e < EB; ++e) acc += (double)qrow[e] * (double)prow[e];
    unsigned long long m = __ballot(acc > 0.0);
    if (b == 0) {
        bits[qi] = (u32)(which ? (m >> 32) : (m & 0xffffffffULL));
    }
}

// ---------------------------------------------------------------------------
// K-means iteration: 128 blocks (16 nh x 8 tiles of 256 points), 256 thr.
// u16-packed partials; packed-key argmin (== first-min); per-set-bit LDS
// histogram of OWN 256 points; packed atomic dump (exact, deterministic).
// ---------------------------------------------------------------------------
__global__ __launch_bounds__(256) void kmeans_iter_kernel(const u32* __restrict__ bits,
                                                          const u32* __restrict__ part_prev,
                                                          u32* __restrict__ part_cur,
                                                          const u32* __restrict__ cent_prev_g,
                                                          u32* __restrict__ cent_cur_g,
                                                          int it) {
    __shared__ u32 cent[CLN];
    __shared__ int hist[33 * 128];       // unpacked [j*128+c]
    int tid = threadIdx.x;
    int bid = blockIdx.x;
    int nh = bid >> 3;
    int tile = bid & 7;
    int lane = tid & 63;

    for (int i = tid; i < 33 * 128; i += 256) hist[i] = 0;
    if (tid < CLN) {
        u32 cv;
        if (it == 0) {
            cv = bits[nh * LB + tid * (LB / CLN)];        // init_idx = 16c
        } else {
            const u32* pp = part_prev + nh * PART_NH16;
            int sh = (tid & 1) * 16;
            int cnt = (int)((pp[32 * 64 + (tid >> 1)] >> sh) & 0xffffu);
            u32 nb = 0u;
            #pragma unroll
            for (int j = 0; j < BITSN; ++j) {
                int s = (int)((pp[j * 64 + (tid >> 1)] >> sh) & 0xffffu);
                if (2 * s >= cnt) nb |= (1u << j);
            }
            cv = (cnt > 0) ? nb : cent_prev_g[nh * CLN + tid];
        }
        cent[tid] = cv;
        if (tile == 0) cent_cur_g[nh * CLN + tid] = cv;   // materialize chain
    }
    __syncthreads();

    int l = tile * 256 + tid;
    u32 bv = bits[nh * LB + l];

    // ---- argmin via packed key (d<<7)|c : min == first-min tie rule
    u32 clo = cent[lane], chi = cent[lane + 64];
    u32 best = 0x7fffffffu;
    #pragma unroll 16
    for (int c = 0; c < 64; ++c) {
        u32 cc = (u32)__builtin_amdgcn_readlane((int)clo, c);
        u32 key = ((u32)__popc(bv ^ cc) << 7) | (u32)c;
        best = (key < best) ? key : best;
    }
    #pragma unroll 16
    for (int c = 0; c < 64; ++c) {
        u32 cc = (u32)__builtin_amdgcn_readlane((int)chi, c);
        u32 key = ((u32)__popc(bv ^ cc) << 7) | (u32)(64 + c);
        best = (key < best) ? key : best;
    }
    int bc = (int)(best & 127u);

    // ---- per-set-bit LDS histogram (exact integer adds)
    atomicAdd(&hist[32 * 128 + bc], 1);
    u32 bb = bv;
    while (bb) { int j = __ffs(bb) - 1; atomicAdd(&hist[j * 128 + bc], 1); bb &= bb - 1; }
    __syncthreads();

    // ---- u16-packed dump (pair c=2p, 2p+1); skip zero pairs
    u32* pc = part_cur + nh * PART_NH16;
    for (int i = tid; i < PART_NH16; i += 256) {
        int j = i >> 6, p = i & 63;
        u32 v = (u32)hist[j * 128 + 2 * p] | ((u32)hist[j * 128 + 2 * p + 1] << 16);
        if (v) atomicAdd(&pc[i], v);
    }
}

// ---------------------------------------------------------------------------
// Kernel 3: final assignment + lists fused, 16 blocks x 1024 thr.
// ---------------------------------------------------------------------------
__global__ __launch_bounds__(1024) void list_final_kernel(const u32* __restrict__ bits,
                                                          const u32* __restrict__ part_prev,
                                                          const u32* __restrict__ cent_prev_g,
                                                          int* __restrict__ csort_g,
                                                          int* __restrict__ cnt_g,
                                                          int* __restrict__ ofs_g,
                                                          int* __restrict__ list_g) {
    __shared__ u32 cent[CLN];
    __shared__ int cnt[CLN];
    __shared__ int cntw[2][16][CLN];       // (group, wave, cluster)
    __shared__ int ofs[CLN];
    int nh = blockIdx.x;
    int tid = threadIdx.x;
    int w = tid >> 6, lane = tid & 63;

    if (tid < CLN) {
        const u32* pp = part_prev + nh * PART_NH16;
        int sh = (tid & 1) * 16;
        int cn = (int)((pp[32 * 64 + (tid >> 1)] >> sh) & 0xffffu);
        u32 nb = 0u;
        #pragma unroll
        for (int j = 0; j < BITSN; ++j) {
            int s = (int)((pp[j * 64 + (tid >> 1)] >> sh) & 0xffffu);
            if (2 * s >= cn) nb |= (1u << j);
        }
        cent[tid] = (cn > 0) ? nb : cent_prev_g[nh * CLN + tid];
        cnt[tid] = 0;
    }
    for (int i = tid; i < 2 * 16 * CLN; i += 1024) (&cntw[0][0][0])[i] = 0;
    __syncthreads();

    int l0 = tid, l1 = tid + 1024;
    u32 bv0 = bits[nh * LB + l0];
    u32 bv1 = bits[nh * LB + l1];
    u32 clo = cent[lane], chi = cent[lane + 64];
    u32 best0 = 0x7fffffffu, best1 = 0x7fffffffu;
    #pragma unroll 16
    for (int c = 0; c < 64; ++c) {
        u32 cc = (u32)__builtin_amdgcn_readlane((int)clo, c);
        u32 k0 = ((u32)__popc(bv0 ^ cc) << 7) | (u32)c;
        u32 k1 = ((u32)__popc(bv1 ^ cc) << 7) | (u32)c;
        best0 = (k0 < best0) ? k0 : best0;
        best1 = (k1 < best1) ? k1 : best1;
    }
    #pragma unroll 16
    for (int c = 0; c < 64; ++c) {
        u32 cc = (u32)__builtin_amdgcn_readlane((int)chi, c);
        u32 k0 = ((u32)__popc(bv0 ^ cc) << 7) | (u32)(64 + c);
        u32 k1 = ((u32)__popc(bv1 ^ cc) << 7) | (u32)(64 + c);
        best0 = (k0 < best0) ? k0 : best0;
        best1 = (k1 < best1) ? k1 : best1;
    }
    int bc0 = (int)(best0 & 127u);
    int bc1 = (int)(best1 & 127u);
    u64 ltmask = (lane == 0) ? 0ULL : (~0ULL >> (64 - lane));

    int rank0 = 0, rank1 = 0;
    for (int c = 0; c < CLN; ++c) {
        u64 m0 = __ballot(bc0 == c);
        u64 m1 = __ballot(bc1 == c);
        if ((m0 | m1) == 0ULL) continue;
        if (bc0 == c) rank0 = (int)__popcll(m0 & ltmask);
        if (bc1 == c) rank1 = (int)__popcll(m1 & ltmask);
        if (lane == 0) {
            int p0 = (int)__popcll(m0), p1 = (int)__popcll(m1);
            if (p0) cntw[0][w][c] = p0;
            if (p1) cntw[1][w][c] = p1;
            atomicAdd(&cnt[c], p0 + p1);
        }
    }
    __syncthreads();
    if (tid == 0) {
        int run = 0;
        for (int c = 0; c < CLN; ++c) { ofs[c] = run; run += cnt[c]; }
    }
    __syncthreads();
    if (tid < CLN) {           // absolute bases per (g,w) in ascending-l order
        int c = tid;
        int run = ofs[c];
        #pragma unroll
        for (int g = 0; g < 2; ++g)
            for (int ww = 0; ww < 16; ++ww) {
                int t = cntw[g][ww][c];
                cntw[g][ww][c] = run;
                run += t;
            }
        cnt_g[nh * CLN + c] = cnt[c];
        ofs_g[nh * CLN + c] = ofs[c];
    }
    __syncthreads();
    {
        int p0 = cntw[0][w][bc0] + rank0;
        int p1 = cntw[1][w][bc1] + rank1;
        list_g[nh * LB + p0] = l0;
        list_g[nh * LB + p1] = l1;
        csort_g[nh * LB + p0] = bc0;        // cluster id at list position
        csort_g[nh * LB + p1] = bc1;
    }
}

// ---------------------------------------------------------------------------
// Kernel 3b: Qg chip-wide. Block per (nh,c) x 4 waves; f64, fixed order.
// ---------------------------------------------------------------------------
__global__ __launch_bounds__(256) void qg_kernel(const float* __restrict__ q,
                                                 const int* __restrict__ cnt_g,
                                                 const int* __restrict__ ofs_g,
                                                 const int* __restrict__ list_g,
                                                 float* __restrict__ qgf) {
    __shared__ double ps[4][EB];
    int bid = blockIdx.x;            // nh*128 + c
    int nh = bid >> 7;
    int h = nh & (HB - 1);
    int n = nh / HB;
    int tid = threadIdx.x;
    int w = tid >> 6, lane = tid & 63;
    int cn = cnt_g[bid];
    int o = ofs_g[bid];
    const int* lp = list_g + nh * LB + o;
    double acc = 0.0;
    for (int i = w; i < cn; i += 4) {
        int l = lp[i];
        acc += (double)q[(((long long)n * LB + l) * HB + h) * EB + lane];
    }
    ps[w][lane] = acc;
    __syncthreads();
    if (tid < EB) {
        double s = ((ps[0][tid] + ps[1][tid]) + ps[2][tid]) + ps[3][tid];
        double dcn = (double)(cn > 0 ? cn : 1);
        qgf[(long long)bid * EB + tid] = (float)(s / dcn);
    }
}

// ---------------------------------------------------------------------------
// Kernel 4: scores with LDS-staged Qg (R20-verified). 512 blocks (nh x 32
// tiles of 64 rows) x 4 waves; block stages the nh's 32 KB Qg in LDS once;
// each wave holds 64 K rows in registers, 32-cluster slice, 4-way split
// accumulators (fixed combine). Coalesced key stores.
// ---------------------------------------------------------------------------
__global__ __launch_bounds__(256) void scores_kernel(const float* __restrict__ kk,
                                                     const float* __restrict__ qgf,
                                                     u32* __restrict__ keys) {
    __shared__ float qs[CLN * EB];   // 32 KB
    int bid = blockIdx.x;            // nh*32 + tile (64-row tiles)
    int nh = bid >> 5;
    int tile = bid & 31;
    int h = nh & (HB - 1);
    int n = nh / HB;
    int tid = threadIdx.x;
    int w = tid >> 6;
    int lane = tid & 63;
    int l = tile * 64 + lane;        // my row
    int cbase = w * 32;              // 32-cluster slice per wave

    // cooperative stage: 2048 float4 = 32 KB, coalesced
    {
        const float4* src = (const float4*)(qgf + (long long)nh * CLN * EB);
        float4* dst = (float4*)qs;
        #pragma unroll
        for (int i = 0; i < 8; ++i) dst[tid + 256 * i] = src[tid + 256 * i];
    }

    const float4* kr4 = (const float4*)(kk + (((long long)n * LB + l) * HB + h) * EB);
    float rr[EB];
    #pragma unroll
    for (int i = 0; i < 16; ++i) {
        float4 t4 = kr4[i];
        rr[4 * i] = t4.x; rr[4 * i + 1] = t4.y; rr[4 * i + 2] = t4.z; rr[4 * i + 3] = t4.w;
    }
    __syncthreads();

    for (int c = 0; c < 32; ++c) {
        const float4* qp = (const float4*)(qs + (cbase + c) * EB);  // LDS broadcast
        float a0 = 0.f, a1 = 0.f, a2 = 0.f, a3 = 0.f;
        #pragma unroll
        for (int i = 0; i < 4; ++i) {
            float4 q0 = qp[i], q1 = qp[4 + i], q2 = qp[8 + i], q3 = qp[12 + i];
            int e0 = 4 * i, e1 = 16 + 4 * i, e2 = 32 + 4 * i, e3 = 48 + 4 * i;
            a0 = fmaf(q0.x, rr[e0], a0); a0 = fmaf(q0.y, rr[e0 + 1], a0);
            a0 = fmaf(q0.z, rr[e0 + 2], a0); a0 = fmaf(q0.w, rr[e0 + 3], a0);
            a1 = fmaf(q1.x, rr[e1], a1); a1 = fmaf(q1.y, rr[e1 + 1], a1);
            a1 = fmaf(q1.z, rr[e1 + 2], a1); a1 = fmaf(q1.w, rr[e1 + 3], a1);
            a2 = fmaf(q2.x, rr[e2], a2); a2 = fmaf(q2.y, rr[e2 + 1], a2);
            a2 = fmaf(q2.z, rr[e2 + 2], a2); a2 = fmaf(q2.w, rr[e2 + 3], a2);
            a3 = fmaf(q3.x, rr[e3], a3); a3 = fmaf(q3.y, rr[e3 + 1], a3);
            a3 = fmaf(q3.z, rr[e3 + 2], a3); a3 = fmaf(q3.w, rr[e3 + 3], a3);
        }
        float acc = (a0 + a1) + (a2 + a3);   // fixed deterministic combine
        u32 u = __float_as_uint(acc);
        u = ((int)u < 0) ? ~u : (u | 0x80000000u);          // monotone f32->u32
        keys[((long long)(nh * CLN + cbase + c)) * LB + l] = u;
    }
}

// ---------------------------------------------------------------------------
// Kernel 5: top-32 per (n,h,c), single-wave tournament with keys in NAMED
// REGISTERS (the R22 array form spilled to scratch: VGPR=40 < 64 needed).
// Same comparator / order -> bit-identical tki to the verified tournament.
// ---------------------------------------------------------------------------
__global__ __launch_bounds__(64) void topsel_kernel(const u32* __restrict__ keys,
                                                    int* __restrict__ tki_g) {
    int bid = blockIdx.x;            // nh*128 + c
    int lane = threadIdx.x;
    const uint4* kp4 = (const uint4*)(keys + (long long)bid * LB);

    u64 k0, k1, k2, k3, k4, k5, k6, k7, k8, k9, k10, k11, k12, k13, k14, k15,
        k16, k17, k18, k19, k20, k21, k22, k23, k24, k25, k26, k27, k28, k29, k30, k31;
#define LOADQ(T, A, B, C, D) { uint4 kv = kp4[lane + 64 * (T)]; int l0 = (lane + 64 * (T)) * 4; \
    A = ((u64)kv.x << 32) | (u32)(2047 - l0); \
    B = ((u64)kv.y << 32) | (u32)(2047 - (l0 + 1)); \
    C = ((u64)kv.z << 32) | (u32)(2047 - (l0 + 2)); \
    D = ((u64)kv.w << 32) | (u32)(2047 - (l0 + 3)); }
    LOADQ(0, k0, k1, k2, k3)   LOADQ(1, k4, k5, k6, k7)
    LOADQ(2, k8, k9, k10, k11) LOADQ(3, k12, k13, k14, k15)
    LOADQ(4, k16, k17, k18, k19) LOADQ(5, k20, k21, k22, k23)
    LOADQ(6, k24, k25, k26, k27) LOADQ(7, k28, k29, k30, k31)
#undef LOADQ

    // initial per-lane max: 4 independent chains, then combine
#define MX(M, X) { if ((X) > (M)) (M) = (X); }
    u64 m0 = k0, m1 = k8, m2 = k16, m3 = k24;
    MX(m0, k1) MX(m0, k2) MX(m0, k3) MX(m0, k4) MX(m0, k5) MX(m0, k6) MX(m0, k7)
    MX(m1, k9) MX(m1, k10) MX(m1, k11) MX(m1, k12) MX(m1, k13) MX(m1, k14) MX(m1, k15)
    MX(m2, k17) MX(m2, k18) MX(m2, k19) MX(m2, k20) MX(m2, k21) MX(m2, k22) MX(m2, k23)
    MX(m3, k25) MX(m3, k26) MX(m3, k27) MX(m3, k28) MX(m3, k29) MX(m3, k30) MX(m3, k31)
#undef MX
    if (m1 > m0) m0 = m1;
    if (m3 > m2) m2 = m3;
    u64 cur = (m2 > m0) ? m2 : m0;

    for (int r = 0; r < TOPKN; ++r) {
        u64 wk = cur;
        #pragma unroll
        for (int off = 1; off < 64; off <<= 1) {
            u64 o = __shfl_xor(wk, off);
            if (o > wk) wk = o;
        }
        if (lane == 0) tki_g[bid * TOPKN + r] = 2047 - (int)(wk & 2047u);
        if (wk == cur) {               // unique owner: implicit-delete rescan
            u64 nm = 0ULL;
#define CK(X) { u64 c2 = ((X) < wk) ? (X) : 0ULL; if (c2 > nm) nm = c2; }
            CK(k0) CK(k1) CK(k2) CK(k3) CK(k4) CK(k5) CK(k6) CK(k7)
            CK(k8) CK(k9) CK(k10) CK(k11) CK(k12) CK(k13) CK(k14) CK(k15)
            CK(k16) CK(k17) CK(k18) CK(k19) CK(k20) CK(k21) CK(k22) CK(k23)
            CK(k24) CK(k25) CK(k26) CK(k27) CK(k28) CK(k29) CK(k30) CK(k31)
#undef CK
            cur = nm;
        }
    }
}

// ---------------------------------------------------------------------------
// Per-query attention body (R15-verified math, byte-identical semantics).
// ---------------------------------------------------------------------------
__device__ __forceinline__ void attn_one(const float* __restrict__ q,
                                         const float* __restrict__ kk,
                                         const float* __restrict__ vv,
                                         int n, int h, int l,
                                         const int* __restrict__ krow,
                                         int lane, float* __restrict__ out) {
    int j = lane & 31, p = lane >> 5;
    int kidx = krow[j];
    const float* vbase = vv + ((long long)n * LB * HB + h) * EB;
    float vreg[TOPKN];
    #pragma unroll
    for (int jj = 0; jj < TOPKN; ++jj) {
        int kj = __shfl(kidx, jj);
        vreg[jj] = vbase[(long long)kj * (HB * EB) + lane];
    }
    const float4* q4 = (const float4*)(q + (((long long)n * LB + l) * HB + h) * EB) + p * 8;
    const float4* k4 = (const float4*)(kk + (((long long)n * LB + kidx) * HB + h) * EB) + p * 8;
    float part = 0.f;
    #pragma unroll
    for (int i = 0; i < 8; ++i) {
        float4 a = q4[i], b = k4[i];
        part += a.x * b.x + a.y * b.y + a.z * b.z + a.w * b.w;
    }
    float qlo = __shfl(part, j);
    float qhi = __shfl(part, j + 32);
    float qk = qlo + qhi;
    bool future = kidx > l;
    float logit = 0.125f * (future ? NEGV : qk);
    float m = logit;
    #pragma unroll
    for (int off = 16; off; off >>= 1) m = fmaxf(m, __shfl_xor(m, off));
    float ex = expf(logit - m);
    float ssum = ex;
    #pragma unroll
    for (int off = 16; off; off >>= 1) ssum += __shfl_xor(ssum, off);
    float a = future ? 0.f : ex / ssum;
    float oacc = 0.f;
    #pragma unroll
    for (int jj = 0; jj < TOPKN; ++jj) {
        float aj = __shfl(a, jj);
        oacc = fmaf(aj, vreg[jj], oacc);
    }
    out[(((long long)n * LB + l) * HB + h) * EB + lane] = oacc;
}

// ---------------------------------------------------------------------------
// Shared-pair attention body (R17-verified shared path, byte-identical).
// ---------------------------------------------------------------------------
__device__ __forceinline__ void attn_pair_body(const float* __restrict__ q,
                                               const float* __restrict__ kk,
                                               const float* __restrict__ vv,
                                               int n, int h, int l0, int l1,
                                               const int* __restrict__ krow,
                                               int lane, float* __restrict__ out) {
    int j = lane & 31, p = lane >> 5;
    int kidx = krow[j];
    const float* vbase = vv + ((long long)n * LB * HB + h) * EB;
    float vreg[TOPKN];
    #pragma unroll
    for (int jj = 0; jj < TOPKN; ++jj) {
        int kj = __shfl(kidx, jj);
        vreg[jj] = vbase[(long long)kj * (HB * EB) + lane];
    }
    const float4* q40 = (const float4*)(q + (((long long)n * LB + l0) * HB + h) * EB) + p * 8;
    const float4* q41 = (const float4*)(q + (((long long)n * LB + l1) * HB + h) * EB) + p * 8;
    const float4* k4  = (const float4*)(kk + (((long long)n * LB + kidx) * HB + h) * EB) + p * 8;
    float part0 = 0.f, part1 = 0.f;
    #pragma unroll
    for (int i = 0; i < 8; ++i) {
        float4 b = k4[i];
        float4 a0 = q40[i], a1 = q41[i];
        part0 += a0.x * b.x + a0.y * b.y + a0.z * b.z + a0.w * b.w;
        part1 += a1.x * b.x + a1.y * b.y + a1.z * b.z + a1.w * b.w;
    }
    float qk0 = __shfl(part0, j) + __shfl(part0, j + 32);
    float qk1 = __shfl(part1, j) + __shfl(part1, j + 32);
    bool fut0 = kidx > l0, fut1 = kidx > l1;
    float lg0 = 0.125f * (fut0 ? NEGV : qk0);
    float lg1 = 0.125f * (fut1 ? NEGV : qk1);
    float m0 = lg0, m1 = lg1;
    #pragma unroll
    for (int off = 16; off; off >>= 1) {
        m0 = fmaxf(m0, __shfl_xor(m0, off));
        m1 = fmaxf(m1, __shfl_xor(m1, off));
    }
    float e0 = expf(lg0 - m0), e1 = expf(lg1 - m1);
    float s0 = e0, s1 = e1;
    #pragma unroll
    for (int off = 16; off; off >>= 1) {
        s0 += __shfl_xor(s0, off);
        s1 += __shfl_xor(s1, off);
    }
    float a0 = fut0 ? 0.f : e0 / s0;
    float a1 = fut1 ? 0.f : e1 / s1;
    float o0 = 0.f, o1 = 0.f;
    #pragma unroll
    for (int jj = 0; jj < TOPKN; ++jj) {
        float aj0 = __shfl(a0, jj);
        float aj1 = __shfl(a1, jj);
        o0 = fmaf(aj0, vreg[jj], o0);
        o1 = fmaf(aj1, vreg[jj], o1);
    }
    out[(((long long)n * LB + l0) * HB + h) * EB + lane] = o0;
    out[(((long long)n * LB + l1) * HB + h) * EB + lane] = o1;
}

// ---------------------------------------------------------------------------
// Kernel 6: QUAD gather attention in CLUSTER-SORTED order. All-same quads
// take the 4-way shared path; mixed quads decompose into per-half pair
// checks (pair shared path or attn_one x2). All branches wave-uniform;
// per-query math byte-identical to the verified kernels.
// ---------------------------------------------------------------------------
__global__ __launch_bounds__(256) void attn_quad_kernel(const float* __restrict__ q,
                                                        const float* __restrict__ kk,
                                                        const float* __restrict__ vv,
                                                        const int* __restrict__ list_g,
                                                        const int* __restrict__ csort_g,
                                                        const int* __restrict__ tki_g,
                                                        float* __restrict__ out) {
    int tid = threadIdx.x;
    int wave = tid >> 6, lane = tid & 63;
    int idx = blockIdx.x * 4 + wave;  // quad index: nh*(L/4) + qd
    int nh = idx >> 9;                // LB/4 = 512 quads per nh
    int qd = idx & 511;
    int pos = 4 * qd;
    int l0 = list_g[nh * LB + pos];
    int l1 = list_g[nh * LB + pos + 1];
    int l2 = list_g[nh * LB + pos + 2];
    int l3 = list_g[nh * LB + pos + 3];
    int c0 = csort_g[nh * LB + pos];
    int c1 = csort_g[nh * LB + pos + 1];
    int c2 = csort_g[nh * LB + pos + 2];
    int c3 = csort_g[nh * LB + pos + 3];
    int h = nh & (HB - 1);
    int n = nh / HB;

    if ((c0 != c1) | (c1 != c2) | (c2 != c3)) {   // wave-uniform decompose
        if (c0 == c1) {
            attn_pair_body(q, kk, vv, n, h, l0, l1, tki_g + (nh * CLN + c0) * TOPKN, lane, out);
        } else {
            attn_one(q, kk, vv, n, h, l0, tki_g + (nh * CLN + c0) * TOPKN, lane, out);
            attn_one(q, kk, vv, n, h, l1, tki_g + (nh * CLN + c1) * TOPKN, lane, out);
        }
        if (c2 == c3) {
            attn_pair_body(q, kk, vv, n, h, l2, l3, tki_g + (nh * CLN + c2) * TOPKN, lane, out);
        } else {
            attn_one(q, kk, vv, n, h, l2, tki_g + (nh * CLN + c2) * TOPKN, lane, out);
            attn_one(q, kk, vv, n, h, l3, tki_g + (nh * CLN + c3) * TOPKN, lane, out);
        }
        return;
    }

    // ---- shared path: one tki row, one V-preload, one K row set
    const int* krow = tki_g + (nh * CLN + c0) * TOPKN;
    int j = lane & 31, p = lane >> 5;
    int kidx = krow[j];
    const float* vbase = vv + ((long long)n * LB * HB + h) * EB;
    float vreg[TOPKN];
    #pragma unroll
    for (int jj = 0; jj < TOPKN; ++jj) {
        int kj = __shfl(kidx, jj);
        vreg[jj] = vbase[(long long)kj * (HB * EB) + lane];
    }

    const float4* q40 = (const float4*)(q + (((long long)n * LB + l0) * HB + h) * EB) + p * 8;
    const float4* q41 = (const float4*)(q + (((long long)n * LB + l1) * HB + h) * EB) + p * 8;
    const float4* q42 = (const float4*)(q + (((long long)n * LB + l2) * HB + h) * EB) + p * 8;
    const float4* q43 = (const float4*)(q + (((long long)n * LB + l3) * HB + h) * EB) + p * 8;
    const float4* k4  = (const float4*)(kk + (((long long)n * LB + kidx) * HB + h) * EB) + p * 8;
    float p0 = 0.f, p1 = 0.f, p2 = 0.f, p3 = 0.f;
    #pragma unroll
    for (int i = 0; i < 8; ++i) {
        float4 b = k4[i];
        float4 a0 = q40[i], a1 = q41[i], a2 = q42[i], a3 = q43[i];
        p0 += a0.x * b.x + a0.y * b.y + a0.z * b.z + a0.w * b.w;
        p1 += a1.x * b.x + a1.y * b.y + a1.z * b.z + a1.w * b.w;
        p2 += a2.x * b.x + a2.y * b.y + a2.z * b.z + a2.w * b.w;
        p3 += a3.x * b.x + a3.y * b.y + a3.z * b.z + a3.w * b.w;
    }
    float qk0 = __shfl(p0, j) + __shfl(p0, j + 32);
    float qk1 = __shfl(p1, j) + __shfl(p1, j + 32);
    float qk2 = __shfl(p2, j) + __shfl(p2, j + 32);
    float qk3 = __shfl(p3, j) + __shfl(p3, j + 32);

    bool f0 = kidx > l0, f1 = kidx > l1, f2 = kidx > l2, f3 = kidx > l3;
    float g0 = 0.125f * (f0 ? NEGV : qk0);
    float g1 = 0.125f * (f1 ? NEGV : qk1);
    float g2 = 0.125f * (f2 ? NEGV : qk2);
    float g3 = 0.125f * (f3 ? NEGV : qk3);
    float m0 = g0, m1 = g1, m2 = g2, m3 = g3;
    #pragma unroll
    for (int off = 16; off; off >>= 1) {
        m0 = fmaxf(m0, __shfl_xor(m0, off));
        m1 = fmaxf(m1, __shfl_xor(m1, off));
        m2 = fmaxf(m2, __shfl_xor(m2, off));
        m3 = fmaxf(m3, __shfl_xor(m3, off));
    }
    float e0 = expf(g0 - m0), e1 = expf(g1 - m1);
    float e2 = expf(g2 - m2), e3 = expf(g3 - m3);
    float s0 = e0, s1 = e1, s2 = e2, s3 = e3;
    #pragma unroll
    for (int off = 16; off; off >>= 1) {
        s0 += __shfl_xor(s0, off);
        s1 += __shfl_xor(s1, off);
        s2 += __shfl_xor(s2, off);
        s3 += __shfl_xor(s3, off);
    }
    float a0 = f0 ? 0.f : e0 / s0;
    float a1 = f1 ? 0.f : e1 / s1;
    float a2 = f2 ? 0.f : e2 / s2;
    float a3 = f3 ? 0.f : e3 / s3;

    float o0 = 0.f, o1 = 0.f, o2 = 0.f, o3 = 0.f;
    #pragma unroll
    for (int jj = 0; jj < TOPKN; ++jj) {
        float v = vreg[jj];
        o0 = fmaf(__shfl(a0, jj), v, o0);
        o1 = fmaf(__shfl(a1, jj), v, o1);
        o2 = fmaf(__shfl(a2, jj), v, o2);
        o3 = fmaf(__shfl(a3, jj), v, o3);
    }
    out[(((long long)n * LB + l0) * HB + h) * EB + lane] = o0;
    out[(((long long)n * LB + l1) * HB + h) * EB + lane] = o1;
    out[(((long long)n * LB + l2) * HB + h) * EB + lane] = o2;
    out[(((long long)n * LB + l3) * HB + h) * EB + lane] = o3;
}

// ---------------------------------------------------------------------------
extern "C" void kernel_launch(void* const* d_in, const int* in_sizes, int n_in,
                              void* d_out, int out_size, void* d_ws, size_t ws_size,
                              hipStream_t stream) {
    const float* q = (const float*)d_in[0];
    const float* k = (const float*)d_in[1];
    const float* v = (const float*)d_in[2];
    const float* planes = (const float*)d_in[3];
    float* out = (float*)d_out;

    const int NQ = NB * HB * LB;                  // 32768
    char* ws = (char*)d_ws;
    u32* bits     = (u32*)(ws);                    // 128 KB
    int* csort_g  = (int*)(ws + 0x20000);          // 128 KB (cluster per position)
    int* cnt_g    = (int*)(ws + 0x40000);          // 8 KB
    int* ofs_g    = (int*)(ws + 0x42000);          // 8 KB
    int* list_g   = (int*)(ws + 0x44000);          // 128 KB
    float* qgf    = (float*)(ws + 0x64000);        // 512 KB
    int* tki_g    = (int*)(ws + 0xE4000);          // 256 KB (2048 x 32 ints)
    u32* keys     = (u32*)(ws + 0x124000);         // 16 MB
    // clustering scratch ALIASES the keys region (dead once scores runs):
    u32* part_all = (u32*)(ws + 0x124000);         // 1.35 MB packed partials
    u32* cents0   = (u32*)(ws + 0x124000 + 0x180000);
    u32* cents1   = (u32*)(ws + 0x124000 + 0x182000);

    bits_zero_kernel<<<BITS_BLOCKS + ZBLOCKS, 256, 0, stream>>>(q, planes, bits, part_all);

    for (int it = 0; it < ITERS; ++it) {
        const u32* pp = part_all + (it == 0 ? 0 : (it - 1)) * PART_ITER16;
        u32* pc       = part_all + it * PART_ITER16;
        const u32* cprev = (it & 1) ? cents0 : cents1;   // cent_{it-1}
        u32* ccur        = (it & 1) ? cents1 : cents0;   // cent_it
        kmeans_iter_kernel<<<NB * HB * 8, 256, 0, stream>>>(bits, pp, pc, cprev, ccur, it);
    }
    // cent_10 from part[9] (carry cent_9, parity 1) + csort + lists
    list_final_kernel<<<NB * HB, 1024, 0, stream>>>(
        bits, part_all + 9 * PART_ITER16, cents1, csort_g, cnt_g, ofs_g, list_g);
    qg_kernel<<<NB * HB * CLN, 256, 0, stream>>>(q, cnt_g, ofs_g, list_g, qgf);
    scores_kernel<<<NB * HB * 32, 256, 0, stream>>>(k, qgf, keys);
    topsel_kernel<<<NB * HB * CLN, 64, 0, stream>>>(keys, tki_g);
    attn_quad_kernel<<<NQ / 16, 256, 0, stream>>>(q, k, v, list_g, csort_g, tki_g, out);
}